// Round 7
// baseline (638.790 us; speedup 1.0000x reference)
//
#include <hip/hip_runtime.h>
#include <math.h>

#define DEV __device__ __forceinline__

using f32x4 = __attribute__((ext_vector_type(4))) float;
using bf8   = __attribute__((ext_vector_type(8))) short;
using bf4   = __attribute__((ext_vector_type(4))) short;

// B=16, CIN=256, N=1024, INNER=512, CTX_N=77, CTX_D=768, HEADS=8, DH=64.
// Seq-major [n][c] bf16 activations; every GEMM is C=A*B^T with K contiguous.
// Self-attention R19: LDS-read-throughput attack. 64-key tiles; waves =
// (rt: 32-row half) x (g: 16-key group for QK / 128-dim group for PV).
//  * QK: each bk LDS read feeds 2 MFMAs (dual row-tiles; aq[2][16]=128 VGPR,
//    legal at launch_bounds(512,1) -> 256 cap. R15/R16 spills explained:
//    (.,2) caps VGPR at 128).
//  * PV: V never touches LDS — B-frags straight from L2 (VT[dim][key]),
//    8-frag rolling window on the VMEM pipe; only 4 ap LDS reads/wave.
//  * KL 2x64KB DMA dbuf (1 chunk-row per instr); PL XOR-swizzled (row&7)
//    so ap b128 reads are 2-way instead of 16-way.
//  * ONE barrier per 64 keys (18 total vs 34) — same hazard audit as R18.
// LDS content per 64 keys: ~8k -> ~2.8k cycles; VMEM overlaps on own pipe.
// mm: R13's proven version (16x16x32, BK=64, global_load_lds(16B), XOR
// swizzle) + dual-weight merge (independent GEMM pairs in one launch).

DEV short f2b(float x) {
  unsigned u = __builtin_bit_cast(unsigned, x);
  u += 0x7FFFu + ((u >> 16) & 1u);
  return (short)(u >> 16);
}
DEV float b2f(short s) {
  unsigned u = ((unsigned)(unsigned short)s) << 16;
  return __builtin_bit_cast(float, u);
}
DEV float ldin(const void* p, size_t i, int f) {
  return f ? reinterpret_cast<const float*>(p)[i]
           : b2f(reinterpret_cast<const short*>(p)[i]);
}

typedef const __attribute__((address_space(1))) void* gas_t;
typedef __attribute__((address_space(3))) void* las_t;
DEV void gl_lds16(const short* g, short* l) {
  __builtin_amdgcn_global_load_lds((gas_t)g, (las_t)l, 16, 0, 0);
}

DEV float wave_sum(float v) {
#pragma unroll
  for (int off = 32; off > 0; off >>= 1) v += __shfl_xor(v, off);
  return v;
}

// ---------------------------------------------------------------------------
__global__ __launch_bounds__(256) void probe_dtype(const unsigned short* __restrict__ x,
                                                   int* __restrict__ flag) {
  __shared__ int cnt;
  if (threadIdx.x == 0) cnt = 0;
  __syncthreads();
  int c = 0;
  for (int i = threadIdx.x; i < 8192; i += 256) {
    int e = (x[i] >> 7) & 0xFF;
    if (e == 0xFF || e == 0x00) ++c;
  }
  atomicAdd(&cnt, c);
  __syncthreads();
  if (threadIdx.x == 0) flag[0] = (cnt >= 4) ? 1 : 0;
}

// ---------------------------------------------------------------------------
__global__ __launch_bounds__(256) void gn_stats_ext(const void* __restrict__ x, size_t off,
                                                    const int* __restrict__ dflag,
                                                    float* __restrict__ stats,
                                                    int cpg, int C, int N, int G) {
  int f = dflag[0];
  int b = blockIdx.x / G;
  int g = blockIdx.x % G;
  size_t base = off + ((size_t)b * C + (size_t)g * cpg) * N;
  int count = cpg * N;
  float s = 0.f, ss = 0.f;
  if (f) {
    const float* p = (const float*)x + base;
    for (int i = threadIdx.x * 4; i < count; i += 1024) {
      float4 v = *(const float4*)&p[i];
      s += v.x + v.y + v.z + v.w;
      ss += v.x * v.x + v.y * v.y + v.z * v.z + v.w * v.w;
    }
  } else {
    const short* p = (const short*)x + base;
    for (int i = threadIdx.x * 8; i < count; i += 2048) {
      bf8 v = *(const bf8*)&p[i];
#pragma unroll
      for (int j = 0; j < 8; ++j) { float t = b2f(v[j]); s += t; ss += t * t; }
    }
  }
  s = wave_sum(s);
  ss = wave_sum(ss);
  __shared__ float r1[4], r2[4];
  int wid = threadIdx.x >> 6, lane = threadIdx.x & 63;
  if (lane == 0) { r1[wid] = s; r2[wid] = ss; }
  __syncthreads();
  if (threadIdx.x == 0) {
    s = r1[0] + r1[1] + r1[2] + r1[3];
    ss = r2[0] + r2[1] + r2[2] + r2[3];
    float mean = s / (float)count;
    float var = ss / (float)count - mean * mean;
    stats[blockIdx.x * 2 + 0] = mean;
    stats[blockIdx.x * 2 + 1] = rsqrtf(fmaxf(var, 0.f) + 1e-5f);
  }
}

__global__ __launch_bounds__(256) void gn_stats2(const short* __restrict__ h1,
                                                 float* __restrict__ stats) {
  int b = blockIdx.x >> 5, g = blockIdx.x & 31;
  int nr = threadIdx.x >> 1, half = (threadIdx.x & 1) * 8;
  float s = 0.f, ss = 0.f;
  for (int n = nr; n < 1024; n += 128) {
    bf8 v = *(const bf8*)&h1[((size_t)b * 1024 + n) * 512 + g * 16 + half];
#pragma unroll
    for (int j = 0; j < 8; ++j) { float t = b2f(v[j]); s += t; ss += t * t; }
  }
  s = wave_sum(s);
  ss = wave_sum(ss);
  __shared__ float r1[4], r2[4];
  int wid = threadIdx.x >> 6, lane = threadIdx.x & 63;
  if (lane == 0) { r1[wid] = s; r2[wid] = ss; }
  __syncthreads();
  if (threadIdx.x == 0) {
    s = r1[0] + r1[1] + r1[2] + r1[3];
    ss = r2[0] + r2[1] + r2[2] + r2[3];
    float mean = s / 16384.f;
    float var = ss / 16384.f - mean * mean;
    stats[blockIdx.x * 2 + 0] = mean;
    stats[blockIdx.x * 2 + 1] = rsqrtf(fmaxf(var, 0.f) + 1e-5f);
  }
}

__global__ __launch_bounds__(256) void make_affine(const float* __restrict__ stats,
                                                   const void* __restrict__ gamma,
                                                   const void* __restrict__ beta,
                                                   const int* __restrict__ dflag,
                                                   float* __restrict__ sA, float* __restrict__ tA,
                                                   int C, int cpg, int total) {
  int f = dflag[0];
  int i = blockIdx.x * blockDim.x + threadIdx.x;
  if (i >= total) return;
  int b = i / C, c = i % C;
  int G = C / cpg;
  int g = c / cpg;
  float mean = stats[(b * G + g) * 2 + 0];
  float rstd = stats[(b * G + g) * 2 + 1];
  float gm = ldin(gamma, c, f);
  float bt = ldin(beta, c, f);
  sA[i] = rstd * gm;
  tA[i] = bt - mean * rstd * gm;
}

// ---------------------------------------------------------------------------
__global__ __launch_bounds__(256) void transpose_affine(const void* __restrict__ x, size_t xoff,
                                                        const int* __restrict__ dflag,
                                                        const float* __restrict__ stats1,
                                                        const void* __restrict__ gamma,
                                                        const void* __restrict__ beta,
                                                        short* __restrict__ xT) {
  int f = dflag[0];
  __shared__ short xs[64 * 264];
  int b = blockIdx.y, n0 = blockIdx.x * 64;
  int tid = threadIdx.x;
  int cl = tid >> 3;
  int nl8 = (tid & 7) * 8;
#pragma unroll
  for (int p = 0; p < 8; ++p) {
    int c = p * 32 + cl;
    float mean = stats1[(b * 32 + (c >> 3)) * 2 + 0];
    float rstd = stats1[(b * 32 + (c >> 3)) * 2 + 1];
    float gm = ldin(gamma, c, f);
    float bt = ldin(beta, c, f);
    float sA = rstd * gm;
    float tA = bt - mean * sA;
    size_t gidx = xoff + ((size_t)b * 256 + c) * 1024 + n0 + nl8;
    float v[8];
    if (f) {
      const float* px = (const float*)x;
      float4 a = *(const float4*)&px[gidx];
      float4 bb = *(const float4*)&px[gidx + 4];
      v[0] = a.x; v[1] = a.y; v[2] = a.z; v[3] = a.w;
      v[4] = bb.x; v[5] = bb.y; v[6] = bb.z; v[7] = bb.w;
    } else {
      bf8 a = *(const bf8*)&((const short*)x)[gidx];
#pragma unroll
      for (int j = 0; j < 8; ++j) v[j] = b2f(a[j]);
    }
#pragma unroll
    for (int j = 0; j < 8; ++j) xs[(nl8 + j) * 264 + c] = f2b(v[j] * sA + tA);
  }
  __syncthreads();
  int nl = tid >> 2, cch = (tid & 3) * 64;
#pragma unroll
  for (int m = 0; m < 8; ++m)
    *(bf8*)&xT[((size_t)b * 1024 + n0 + nl) * 256 + cch + m * 8] =
        *(const bf8*)&xs[nl * 264 + cch + m * 8];
}

__global__ __launch_bounds__(256) void affine_apply(const short* __restrict__ h1,
                                                    const float* __restrict__ s2,
                                                    const float* __restrict__ t2,
                                                    short* __restrict__ out) {
  size_t gid = (size_t)blockIdx.x * 256 + threadIdx.x;
  size_t base = gid * 8;
  int bl = (int)(base >> 19);
  int c = (int)(base & 511);
  bf8 v = *(const bf8*)&h1[base];
  bf8 o;
#pragma unroll
  for (int j = 0; j < 8; ++j)
    o[j] = f2b(b2f(v[j]) * s2[bl * 512 + c + j] + t2[bl * 512 + c + j]);
  *(bf8*)&out[base] = o;
}

// ---------------------------------------------------------------------------
// Generic MFMA GEMM (R13 version, proven): OUT[z][p][q] = scale *
// sum_k Bm[p][k]*Am[q][k]. BK=64, global_load_lds(16B) staging, 8-chunk XOR
// swizzle, 16x16x32 MFMA. Dual-weight merge: if blockIdx.y >= ysplit, use
// Am2/Out2 with p-tile index (blockIdx.y - ysplit) — merges independent
// GEMM pairs that share the B operand into one launch (kills a stream tail).
template <int A_EXT, int B_EXT, int OUT_T, int BIAS_P_, int BIAS_Q_, int RES_T>
__global__ __launch_bounds__(256) void mm(
    const void* __restrict__ Am, size_t aoff, int lda, size_t zsa,
    const void* __restrict__ Bm, size_t boff, int ldb, size_t zsb,
    void* __restrict__ Out, size_t ooff, int ldc, size_t zsc,
    const void* __restrict__ Res, size_t roff, size_t zsr, float res_scale,
    const void* __restrict__ biasP, const void* __restrict__ biasQ,
    const int* __restrict__ dflag, float scale, int P, int K,
    const void* __restrict__ Am2, void* __restrict__ Out2, int ysplit) {
  const int f = dflag[0];
  __shared__ short lA[128 * 64];
  __shared__ short lB[128 * 64];
  const int tid = threadIdx.x;
  const int z = blockIdx.z;
  int yy = blockIdx.y;
  const void* Ause = Am;
  void* Ouse = Out;
  if (yy >= ysplit) { Ause = Am2; Ouse = Out2; yy -= ysplit; }
  const int q0 = blockIdx.x * 128, p0 = yy * 128;
  const int l = tid & 63;
  const int w = tid >> 6;
  const int wq = (w & 1) * 64, wp = (w >> 1) * 64;
  const int lm = l & 15, quad = l >> 4;
  const int drow = l >> 3;
  const int gchunk = (l & 7) ^ ((l >> 3) & 7);
  const int rx = lm & 7;

  f32x4 acc[4][4];
#pragma unroll
  for (int i = 0; i < 4; ++i)
#pragma unroll
    for (int j = 0; j < 4; ++j) acc[i][j] = (f32x4){0.f, 0.f, 0.f, 0.f};

  for (int kk = 0; kk < K; kk += 64) {
    __syncthreads();
    // ---- stage A tile (rows q0..q0+127, always valid; A = Ause) ----
    if (!(A_EXT && f)) {
      const short* As = (const short*)Ause;
#pragma unroll
      for (int t = 0; t < 4; ++t) {
        int rl = w * 32 + t * 8;
        size_t g = aoff + (size_t)z * zsa + (size_t)(q0 + rl + drow) * lda + kk + gchunk * 8;
        gl_lds16(As + g, &lA[rl * 64]);
      }
    } else {
      const float* p = (const float*)Ause;
      int r = tid >> 1;
      size_t g = aoff + (size_t)z * zsa + (size_t)(q0 + r) * lda + kk;
#pragma unroll
      for (int ci = 0; ci < 4; ++ci) {
        int pc = (tid & 1) * 4 + ci;
        int gc = pc ^ (r & 7);
        short tmp[8];
#pragma unroll
        for (int i2 = 0; i2 < 8; i2 += 4) {
          float4 t4 = *(const float4*)&p[g + gc * 8 + i2];
          tmp[i2] = f2b(t4.x); tmp[i2 + 1] = f2b(t4.y);
          tmp[i2 + 2] = f2b(t4.z); tmp[i2 + 3] = f2b(t4.w);
        }
        *(bf8*)&lA[r * 64 + pc * 8] = *(bf8*)&tmp[0];
      }
    }
    // ---- stage B tile (rows p0..p0+127, guard >= P) ----
    if (!(B_EXT && f)) {
      const short* Bs = (const short*)Bm;
#pragma unroll
      for (int t = 0; t < 4; ++t) {
        int rl = w * 32 + t * 8;
        int r = rl + drow;
        if (p0 + r < P) {
          size_t g = boff + (size_t)z * zsb + (size_t)(p0 + r) * ldb + kk + gchunk * 8;
          gl_lds16(Bs + g, &lB[rl * 64]);
        }
      }
    } else {
      const float* p = (const float*)Bm;
      int r = tid >> 1;
      bool valid = (p0 + r) < P;
      size_t g = boff + (size_t)z * zsb + (size_t)(p0 + r) * ldb + kk;
#pragma unroll
      for (int ci = 0; ci < 4; ++ci) {
        int pc = (tid & 1) * 4 + ci;
        int gc = pc ^ (r & 7);
        short tmp[8] = {0, 0, 0, 0, 0, 0, 0, 0};
        if (valid) {
#pragma unroll
          for (int i2 = 0; i2 < 8; i2 += 4) {
            float4 t4 = *(const float4*)&p[g + gc * 8 + i2];
            tmp[i2] = f2b(t4.x); tmp[i2 + 1] = f2b(t4.y);
            tmp[i2 + 2] = f2b(t4.z); tmp[i2 + 3] = f2b(t4.w);
          }
        }
        *(bf8*)&lB[r * 64 + pc * 8] = *(bf8*)&tmp[0];
      }
    }
    __syncthreads();  // drains vmcnt (DMA) + lgkmcnt before reads

#pragma unroll
    for (int s = 0; s < 2; ++s) {
      bf8 af[4], bfr[4];
#pragma unroll
      for (int i = 0; i < 4; ++i)
        af[i] = *(const bf8*)&lA[(wq + i * 16 + lm) * 64 + (((s * 4 + quad) ^ rx) * 8)];
#pragma unroll
      for (int i = 0; i < 4; ++i)
        bfr[i] = *(const bf8*)&lB[(wp + i * 16 + lm) * 64 + (((s * 4 + quad) ^ rx) * 8)];
#pragma unroll
      for (int qi = 0; qi < 4; ++qi)
#pragma unroll
        for (int pi = 0; pi < 4; ++pi)
          acc[qi][pi] = __builtin_amdgcn_mfma_f32_16x16x32_bf16(af[qi], bfr[pi], acc[qi][pi], 0, 0, 0);
    }
  }

  const size_t obase = ooff + (size_t)z * zsc;
#pragma unroll
  for (int pi = 0; pi < 4; ++pi) {
    int p = p0 + wp + pi * 16 + lm;
    if (p >= P) continue;
    float bp = BIAS_P_ ? ldin(biasP, p, f) : 0.f;
#pragma unroll
    for (int qi = 0; qi < 4; ++qi) {
      int q = q0 + wq + qi * 16 + quad * 4;
      f32x4 d = acc[qi][pi];
      float v[4];
#pragma unroll
      for (int r = 0; r < 4; ++r) {
        v[r] = d[r] * scale + bp;
        if (BIAS_Q_) v[r] += ldin(biasQ, q + r, f);
      }
      if (RES_T == 1) {
        bf4 rv = *(const bf4*)&reinterpret_cast<const short*>(Res)[roff + (size_t)z * zsr + (size_t)p * ldc + q];
#pragma unroll
        for (int r = 0; r < 4; ++r) v[r] += res_scale * b2f(rv[r]);
      } else if (RES_T == 2) {
        size_t ri = roff + (size_t)z * zsr + (size_t)p * ldc + q;
        if (f) {
          float4 rf = *(const float4*)&reinterpret_cast<const float*>(Res)[ri];
          v[0] += res_scale * rf.x; v[1] += res_scale * rf.y;
          v[2] += res_scale * rf.z; v[3] += res_scale * rf.w;
        } else {
          bf4 rv = *(const bf4*)&reinterpret_cast<const short*>(Res)[ri];
#pragma unroll
          for (int r = 0; r < 4; ++r) v[r] += res_scale * b2f(rv[r]);
        }
      }
      size_t idx = obase + (size_t)p * ldc + q;
      if (OUT_T == 0) {
        bf4 o;
#pragma unroll
        for (int r = 0; r < 4; ++r) o[r] = f2b(v[r]);
        *(bf4*)&reinterpret_cast<short*>(Ouse)[idx] = o;
      } else if (OUT_T == 1) {
        f32x4 o = {v[0], v[1], v[2], v[3]};
        *(f32x4*)&reinterpret_cast<float*>(Ouse)[idx] = o;
      } else {
        if (f) {
          f32x4 o = {v[0], v[1], v[2], v[3]};
          *(f32x4*)&reinterpret_cast<float*>(Ouse)[idx] = o;
        } else {
          bf4 o;
#pragma unroll
          for (int r = 0; r < 4; ++r) o[r] = f2b(v[r]);
          *(bf4*)&reinterpret_cast<short*>(Ouse)[idx] = o;
        }
      }
    }
  }
}

// ---------------------------------------------------------------------------
// Fused flash self-attention R19. 512 threads = 8 waves = (rt in 0..1: 32-row
// half) x (g in 0..3: 16-key group for QK / 128-dim group for PV). 64-key
// tiles, 16 iterations, ONE barrier each.
//   QK: wave (rt,g): 32 rows x 16 keys over K=512. 16 bk reads from
//     KL (chunk-major [c][key][8], DMA dbuf 2x64KB), each feeding 2 MFMAs
//     (dual row-tiles via aq[2][16], 128 VGPR).
//   PL[2][64][64]: XOR-swizzled (16B block idx ^= row&7) — ap b128 reads
//     2-way instead of 16-way; scalar b16 writes conflict-free.
//   PV: wave (rt,g=dim-group): 32 rows x 128 dims x 64 keys. V B-frags
//     straight from global VT[dim][key] (L2-resident) — 8-frag rolling
//     window; each bv feeds 2 MFMAs. Only 4 ap LDS reads per wave.
// Deferred normalization: lsum per (row, key-group) -> LS[4][64], combined
// once at the end. launch_bounds(512,1): VGPR cap 256 (8 waves/CU still fit).
__global__ __launch_bounds__(512, 1) void flash_attn(const short* __restrict__ Q,
                                                     const short* __restrict__ Kb,
                                                     const short* __restrict__ VT,
                                                     short* __restrict__ O,
                                                     float scale, int NBm1) {
  __shared__ short KL[2][64 * 512];  // [buf][c=dim/8][key 0..63][8] = 64 KB
  __shared__ short PL[2][64 * 64];   // [buf][row][key] XOR-swizzled, 8 KB
  __shared__ float LS[4][64];        // [key-group][row] partial sums
  const int lin = blockIdx.x;
  const int b = lin & NBm1;
  const int i0 = (lin >> (31 - __builtin_clz(NBm1 + 1))) * 64;
  const int tid = threadIdx.x;
  const int w = tid >> 6, l = tid & 63, lm = l & 15, quad = l >> 4;
  const int rt = w >> 2, g = w & 3;

  const short* kbase = Kb + (size_t)b * 524288;
  const short* vbase = VT + (size_t)b * 524288;

  // Q A-frags: 2 row-tiles (rt*32 + t2*16 + lm), all 512 dims. 128 VGPR.
  bf8 aq[2][16];
#pragma unroll
  for (int t2 = 0; t2 < 2; ++t2) {
    const short* qb = Q + ((size_t)b * 1024 + i0 + rt * 32 + t2 * 16 + lm) * 512;
#pragma unroll
    for (int kc = 0; kc < 16; ++kc) aq[t2][kc] = *(const bf8*)&qb[kc * 32 + quad * 8];
  }

  f32x4 oacc[16];  // [t2*8 + df]: rows rt*32+t2*16, dims g*128+df*16
#pragma unroll
  for (int i = 0; i < 16; ++i) oacc[i] = (f32x4){0.f, 0.f, 0.f, 0.f};
  float lsum[2][4] = {{0.f, 0.f, 0.f, 0.f}, {0.f, 0.f, 0.f, 0.f}};

  // prologue DMA: keys 0..63 -> KL[0]; wave w stages chunk-rows w*8..+8
  // (one instr writes 64 lanes x 16B = one full [key][8] row of a chunk).
#pragma unroll
  for (int i = 0; i < 8; ++i) {
    int c = w * 8 + i;
    gl_lds16(kbase + (size_t)l * 512 + c * 8, &KL[0][c * 512]);
  }
  __syncthreads();

  for (int t = 0; t < 16; ++t) {
    const int p = t & 1;
    const int j0 = t * 64;
    if (t < 15) {
#pragma unroll
      for (int i = 0; i < 8; ++i) {
        int c = w * 8 + i;
        gl_lds16(kbase + (size_t)(j0 + 64 + l) * 512 + c * 8, &KL[p ^ 1][c * 512]);
      }
    }
    // V prefetch: first 32-key chunk of this tile (dims g*128..+128)
    bf8 bva[8];
#pragma unroll
    for (int df = 0; df < 8; ++df)
      bva[df] = *(const bf8*)&vbase[(size_t)(g * 128 + df * 16 + lm) * 1024 + j0 + quad * 8];

    // ---- QK: 32 rows x 16 keys, K=512; each bk feeds both row-tiles ----
    f32x4 s0 = (f32x4){0.f, 0.f, 0.f, 0.f};
    f32x4 s1 = (f32x4){0.f, 0.f, 0.f, 0.f};
    __builtin_amdgcn_s_setprio(1);
#pragma unroll
    for (int kc = 0; kc < 16; ++kc) {
      bf8 bk = *(const bf8*)&KL[p][(kc * 4 + quad) * 512 + (g * 16 + lm) * 8];
      s0 = __builtin_amdgcn_mfma_f32_16x16x32_bf16(aq[0][kc], bk, s0, 0, 0, 0);
      s1 = __builtin_amdgcn_mfma_f32_16x16x32_bf16(aq[1][kc], bk, s1, 0, 0, 0);
    }
    __builtin_amdgcn_s_setprio(0);

    // ---- exp + partial row-sum + swizzled PL write ----
#pragma unroll
    for (int t2 = 0; t2 < 2; ++t2) {
      f32x4 sa = t2 ? s1 : s0;
#pragma unroll
      for (int r = 0; r < 4; ++r) {
        float e = __expf(sa[r] * scale);
        float ts = e;
        ts += __shfl_xor(ts, 1);
        ts += __shfl_xor(ts, 2);
        ts += __shfl_xor(ts, 4);
        ts += __shfl_xor(ts, 8);
        lsum[t2][r] += ts;
        int row = rt * 32 + t2 * 16 + quad * 4 + r;
        int blk = (g * 2 + (lm >> 3)) ^ (row & 7);
        PL[p][row * 64 + blk * 8 + (lm & 7)] = f2b(e);
      }
    }
    __syncthreads();  // single barrier: PL visible, KL DMA(t+1) drained

    // ---- PV: 32 rows x 128 dims, K = 64 keys ----
    bf8 ap[2][2];
#pragma unroll
    for (int t2 = 0; t2 < 2; ++t2) {
      int row = rt * 32 + t2 * 16 + lm;
#pragma unroll
      for (int kc = 0; kc < 2; ++kc)
        ap[t2][kc] = *(const bf8*)&PL[p][row * 64 + (((kc * 4 + quad) ^ (row & 7)) * 8)];
    }
    bf8 bvb[8];
    __builtin_amdgcn_s_setprio(1);
#pragma unroll
    for (int df = 0; df < 8; ++df) {
      bvb[df] = *(const bf8*)&vbase[(size_t)(g * 128 + df * 16 + lm) * 1024 + j0 + 32 + quad * 8];
      oacc[df]     = __builtin_amdgcn_mfma_f32_16x16x32_bf16(ap[0][0], bva[df], oacc[df], 0, 0, 0);
      oacc[8 + df] = __builtin_amdgcn_mfma_f32_16x16x32_bf16(ap[1][0], bva[df], oacc[8 + df], 0, 0, 0);
    }
#pragma unroll
    for (int df = 0; df < 8; ++df) {
      oacc[df]     = __builtin_amdgcn_mfma_f32_16x16x32_bf16(ap[0][1], bvb[df], oacc[df], 0, 0, 0);
      oacc[8 + df] = __builtin_amdgcn_mfma_f32_16x16x32_bf16(ap[1][1], bvb[df], oacc[8 + df], 0, 0, 0);
    }
    __builtin_amdgcn_s_setprio(0);
    // no trailing barrier: next iteration writes the OTHER KL/PL buffers.
  }

  // combine per-key-group row sums, normalize, write out
  if (lm == 0) {
#pragma unroll
    for (int t2 = 0; t2 < 2; ++t2)
#pragma unroll
      for (int r = 0; r < 4; ++r)
        LS[g][rt * 32 + t2 * 16 + quad * 4 + r] = lsum[t2][r];
  }
  __syncthreads();
  short* ob = O + ((size_t)b * 1024 + i0) * 512 + g * 128;
#pragma unroll
  for (int t2 = 0; t2 < 2; ++t2)
#pragma unroll
    for (int r = 0; r < 4; ++r) {
      int row = rt * 32 + t2 * 16 + quad * 4 + r;
      float inv = 1.f / (LS[0][row] + LS[1][row] + LS[2][row] + LS[3][row]);
#pragma unroll
      for (int df = 0; df < 8; ++df)
        ob[(size_t)row * 512 + df * 16 + lm] = f2b(oacc[t2 * 8 + df][r] * inv);
    }
}

// ---------------------------------------------------------------------------
// Fused cross-attention via MFMA (unchanged).
__global__ __launch_bounds__(256) void cross_attn_mfma(const short* __restrict__ q2,
                                                       const short* __restrict__ k2,
                                                       const short* __restrict__ v2,
                                                       short* __restrict__ o2) {
  __shared__ short Pl[64 * 104];
  __shared__ short VTl[64 * 104];
  const int b = blockIdx.z, h = blockIdx.y, i0 = blockIdx.x * 64;
  const int tid = threadIdx.x;
  const int w = tid >> 6, l = tid & 63, lm = l & 15, quad = l >> 4;

  for (int idx = tid; idx < 64 * 104 / 4; idx += 256)
    *(bf4*)&VTl[idx * 4] = (bf4){0, 0, 0, 0};
  __syncthreads();
  for (int idx = tid; idx < 77 * 64; idx += 256) {
    int j = idx >> 6, d = idx & 63;
    VTl[d * 104 + j] = v2[(size_t)b * 39424 + j * 512 + h * 64 + d];
  }

  const short* qb = q2 + ((size_t)b * 1024 + i0 + w * 16 + lm) * 512 + h * 64;
  bf8 aq0 = *(const bf8*)&qb[quad * 8];
  bf8 aq1 = *(const bf8*)&qb[32 + quad * 8];
  const short* kb = k2 + (size_t)b * 39424 + h * 64;
  f32x4 sacc[5];
#pragma unroll
  for (int jt = 0; jt < 5; ++jt) sacc[jt] = (f32x4){0.f, 0.f, 0.f, 0.f};
#pragma unroll
  for (int jt = 0; jt < 5; ++jt) {
    int j = jt * 16 + lm;
    bf8 b0 = {0, 0, 0, 0, 0, 0, 0, 0}, b1 = {0, 0, 0, 0, 0, 0, 0, 0};
    if (j < 77) {
      b0 = *(const bf8*)&kb[j * 512 + quad * 8];
      b1 = *(const bf8*)&kb[j * 512 + 32 + quad * 8];
    }
    sacc[jt] = __builtin_amdgcn_mfma_f32_16x16x32_bf16(aq0, b0, sacc[jt], 0, 0, 0);
    sacc[jt] = __builtin_amdgcn_mfma_f32_16x16x32_bf16(aq1, b1, sacc[jt], 0, 0, 0);
  }
#pragma unroll
  for (int jt = 0; jt < 5; ++jt) {
    bool valid = (jt * 16 + lm) < 77;
#pragma unroll
    for (int r = 0; r < 4; ++r)
      sacc[jt][r] = valid ? sacc[jt][r] * 0.125f : -1e30f;
  }
#pragma unroll
  for (int r = 0; r < 4; ++r) {
    float mx = sacc[0][r];
#pragma unroll
    for (int jt = 1; jt < 5; ++jt) mx = fmaxf(mx, sacc[jt][r]);
    mx = fmaxf(mx, __shfl_xor(mx, 1));
    mx = fmaxf(mx, __shfl_xor(mx, 2));
    mx = fmaxf(mx, __shfl_xor(mx, 4));
    mx = fmaxf(mx, __shfl_xor(mx, 8));
    float s = 0.f;
    float e[5];
#pragma unroll
    for (int jt = 0; jt < 5; ++jt) { e[jt] = __expf(sacc[jt][r] - mx); s += e[jt]; }
    s += __shfl_xor(s, 1);
    s += __shfl_xor(s, 2);
    s += __shfl_xor(s, 4);
    s += __shfl_xor(s, 8);
    float iv = 1.f / s;
    int row = w * 16 + quad * 4 + r;
#pragma unroll
    for (int jt = 0; jt < 5; ++jt) Pl[row * 104 + jt * 16 + lm] = f2b(e[jt] * iv);
  }
#pragma unroll
  for (int r = 0; r < 4; ++r) Pl[(w * 16 + quad * 4 + r) * 104 + 80 + lm] = 0;
  __syncthreads();

  f32x4 oacc[4];
#pragma unroll
  for (int dt = 0; dt < 4; ++dt) oacc[dt] = (f32x4){0.f, 0.f, 0.f, 0.f};
#pragma unroll
  for (int kc = 0; kc < 3; ++kc) {
    bf8 ap = *(const bf8*)&Pl[(w * 16 + lm) * 104 + kc * 32 + quad * 8];
#pragma unroll
    for (int dt = 0; dt < 4; ++dt) {
      bf8 bv = *(const bf8*)&VTl[(dt * 16 + lm) * 104 + kc * 32 + quad * 8];
      oacc[dt] = __builtin_amdgcn_mfma_f32_16x16x32_bf16(ap, bv, oacc[dt], 0, 0, 0);
    }
  }
  short* ob = o2 + ((size_t)b * 1024 + i0 + w * 16 + quad * 4) * 512 + h * 64;
#pragma unroll
  for (int dt = 0; dt < 4; ++dt)
#pragma unroll
    for (int r = 0; r < 4; ++r)
      ob[(size_t)r * 512 + dt * 16 + lm] = f2b(oacc[dt][r]);
}

// ---------------------------------------------------------------------------
extern "C" void kernel_launch(void* const* d_in, const int* in_sizes, int n_in,
                              void* d_out, int out_size, void* d_ws, size_t ws_size,
                              hipStream_t stream) {
  const void* x       = d_in[0];
  const void* ctx     = d_in[1];
  const void* gn1_g   = d_in[2];
  const void* gn1_b   = d_in[3];
  const void* w_in    = d_in[4];
  const void* b_in    = d_in[5];
  const void* sa_wk   = d_in[6];
  const void* sa_wq   = d_in[7];
  const void* sa_wv   = d_in[8];
  const void* sa_wp   = d_in[9];
  const void* sa_gn_g = d_in[10];
  const void* sa_gn_b = d_in[11];
  const void* ca_wq   = d_in[12];
  const void* ca_wk   = d_in[13];
  const void* ca_wv   = d_in[14];
  const void* ca_wo   = d_in[15];
  const void* ca_bo   = d_in[16];
  const void* w_out   = d_in[17];
  const void* b_out   = d_in[18];

  const int B = 16;
  int NB = 16;
  while (NB > 1 && 131072ull + (size_t)NB * 5767168ull > ws_size) NB >>= 1;

  char* base = reinterpret_cast<char*>(d_ws);
  int* flagp = reinterpret_cast<int*>(base);
  float* smf = reinterpret_cast<float*>(base + 1024);
  float* stats1 = smf;
  float* stats2 = smf + 1024;
  float* s2 = smf + 10240;
  float* t2 = smf + 18432;
  char* big = base + 131072;
  const size_t MB = 1048576;
  short* U0 = (short*)(big + 0 * (size_t)NB * MB);
  short* U1 = (short*)(big + 1 * (size_t)NB * MB);
  short* U2 = (short*)(big + 2 * (size_t)NB * MB);
  short* U3 = (short*)(big + 3 * (size_t)NB * MB);
  short* U4 = (short*)(big + 4 * (size_t)NB * MB);
  char* Sreg = big + 5 * (size_t)NB * MB;
  short* xT = (short*)Sreg;
  short* k2 = (short*)Sreg;
  short* v2 = (short*)(Sreg + (size_t)NB * 78848);

  probe_dtype<<<1, 256, 0, stream>>>((const unsigned short*)x, flagp);

  const float qk_scale = 0.044194173824159216f;
  const int NOSPLIT = 1 << 30;

  for (int b0 = 0; b0 < B; b0 += NB) {
    size_t xoff = (size_t)b0 * 262144;
    size_t coff = (size_t)b0 * 59136;

    gn_stats_ext<<<NB * 32, 256, 0, stream>>>(x, xoff, flagp, stats1, 8, 256, 1024, 32);
    transpose_affine<<<dim3(16, NB), 256, 0, stream>>>(x, xoff, flagp, stats1, gn1_g, gn1_b, xT);
    mm<1, 0, 0, 0, 1, 0><<<dim3(4, 8, NB), 256, 0, stream>>>(
        w_in, 0, 256, 0, xT, 0, 256, 262144, U0, 0, 512, 524288,
        nullptr, 0, 0, 0.f, nullptr, b_in, flagp, 1.f, 1024, 256,
        w_in, U0, NOSPLIT);

    gn_stats2<<<NB * 32, 256, 0, stream>>>(U0, stats2);
    make_affine<<<(NB * 512 + 255) / 256, 256, 0, stream>>>(stats2, sa_gn_g, sa_gn_b, flagp, s2, t2, 512, 16, NB * 512);
    affine_apply<<<NB * 256, 256, 0, stream>>>(U0, s2, t2, U1);

    // q + k merged (independent, share B operand U1): y<8 -> q(U2), y>=8 -> k(U3)
    mm<1, 0, 0, 0, 0, 0><<<dim3(4, 16, NB), 256, 0, stream>>>(
        sa_wq, 0, 512, 0, U1, 0, 512, 524288, U2, 0, 512, 524288,
        nullptr, 0, 0, 0.f, nullptr, nullptr, flagp, 1.f, 1024, 512,
        sa_wk, U3, 8);
    mm<0, 1, 0, 0, 0, 0><<<dim3(8, 4, NB), 256, 0, stream>>>(
        U1, 0, 512, 524288, sa_wv, 0, 512, 0, U4, 0, 1024, 524288,
        nullptr, 0, 0, 0.f, nullptr, nullptr, flagp, 1.f, 512, 512,
        U1, U4, NOSPLIT);

    flash_attn<<<dim3(16 * NB), 512, 0, stream>>>(U2, U3, U4, U1, qk_scale, NB - 1);

    mm<1, 0, 0, 0, 0, 1><<<dim3(4, 8, NB), 256, 0, stream>>>(
        sa_wp, 0, 512, 0, U1, 0, 512, 524288, U3, 0, 512, 524288,
        U0, 0, 524288, 2.f, nullptr, nullptr, flagp, 1.f, 1024, 512,
        sa_wp, U3, NOSPLIT);

    mm<1, 0, 0, 0, 0, 0><<<dim3(4, 8, NB), 256, 0, stream>>>(
        ca_wq, 0, 512, 0, U3, 0, 512, 524288, U2, 0, 512, 524288,
        nullptr, 0, 0, 0.f, nullptr, nullptr, flagp, 1.f, 1024, 512,
        ca_wq, U2, NOSPLIT);
    // ca_wk + ca_wv merged (independent, share B operand ctx): y=0 -> k2, y=1 -> v2
    mm<1, 1, 0, 0, 0, 0><<<dim3(4, 2, NB), 256, 0, stream>>>(
        ca_wk, 0, 768, 0, ctx, coff, 768, 59136, k2, 0, 512, 39424,
        nullptr, 0, 0, 0.f, nullptr, nullptr, flagp, 1.f, 77, 768,
        ca_wv, v2, 1);
    cross_attn_mfma<<<dim3(16, 8, NB), 256, 0, stream>>>(U2, k2, v2, U4);

    mm<1, 0, 0, 0, 1, 1><<<dim3(4, 8, NB), 256, 0, stream>>>(
        ca_wo, 0, 512, 0, U4, 0, 512, 524288, U0, 0, 512, 524288,
        U3, 0, 524288, 1.f, nullptr, ca_bo, flagp, 1.f, 1024, 512,
        ca_wo, U0, NOSPLIT);

    mm<0, 1, 2, 1, 0, 2><<<dim3(8, 2, NB), 256, 0, stream>>>(
        U0, 0, 512, 524288, w_out, 0, 512, 0, d_out, xoff, 1024, 262144,
        x, xoff, 262144, 1.f, b_out, nullptr, flagp, 1.f, 256, 512,
        U0, d_out, NOSPLIT);
  }

  (void)in_sizes; (void)n_in; (void)out_size;
}

// Round 8
// 599.992 us; speedup vs baseline: 1.0647x; 1.0647x over previous
//
#include <hip/hip_runtime.h>
#include <math.h>

#define DEV __device__ __forceinline__

using f32x4  = __attribute__((ext_vector_type(4))) float;
using f32x16 = __attribute__((ext_vector_type(16))) float;
using bf8    = __attribute__((ext_vector_type(8))) short;
using bf4    = __attribute__((ext_vector_type(4))) short;

// B=16, CIN=256, N=1024, INNER=512, CTX_N=77, CTX_D=768, HEADS=8, DH=64.
// Seq-major [n][c] bf16 activations; every GEMM is C=A*B^T with K contiguous.
// Self-attention R20: 32x32x16 MFMA + wave specialization.
//  waves 0-3: QK producers — S^T = mfma(A=K, B=Q) per 32x32 tile (rt,kh),
//    K=512 in 2 passes of 256 (Q reloaded from L2 -> aq only 64 VGPR);
//    exp + row-sum are lane-local in the S^T layout; P^T -> PL (XOR swz).
//  waves 4-7: PV consumers — O^T = mfma(A=V^T from L2, B=P^T from PL);
//    V never touches LDS; oacc 8x f32x16 (128 acc regs, PV branch only).
//  Specialization PARTITIONS the register budget (union ~218 <= 256; the
//  R15/R16/R19 spills all came from summing QK+PV state in one wave).
//  KL[2] 64-key DMA dbuf; ONE barrier per tile; QK(t) || PV(t-1) pipeline.
//  Epilogue: O^T -> O transpose through dead KL space (coalesced store).
// mm: R13's proven version (16x16x32, BK=64, global_load_lds(16B), XOR
// swizzle) + dual-weight merge (independent GEMM pairs in one launch).

DEV short f2b(float x) {
  unsigned u = __builtin_bit_cast(unsigned, x);
  u += 0x7FFFu + ((u >> 16) & 1u);
  return (short)(u >> 16);
}
DEV float b2f(short s) {
  unsigned u = ((unsigned)(unsigned short)s) << 16;
  return __builtin_bit_cast(float, u);
}
DEV float ldin(const void* p, size_t i, int f) {
  return f ? reinterpret_cast<const float*>(p)[i]
           : b2f(reinterpret_cast<const short*>(p)[i]);
}

typedef const __attribute__((address_space(1))) void* gas_t;
typedef __attribute__((address_space(3))) void* las_t;
DEV void gl_lds16(const short* g, short* l) {
  __builtin_amdgcn_global_load_lds((gas_t)g, (las_t)l, 16, 0, 0);
}

DEV float wave_sum(float v) {
#pragma unroll
  for (int off = 32; off > 0; off >>= 1) v += __shfl_xor(v, off);
  return v;
}

// ---------------------------------------------------------------------------
__global__ __launch_bounds__(256) void probe_dtype(const unsigned short* __restrict__ x,
                                                   int* __restrict__ flag) {
  __shared__ int cnt;
  if (threadIdx.x == 0) cnt = 0;
  __syncthreads();
  int c = 0;
  for (int i = threadIdx.x; i < 8192; i += 256) {
    int e = (x[i] >> 7) & 0xFF;
    if (e == 0xFF || e == 0x00) ++c;
  }
  atomicAdd(&cnt, c);
  __syncthreads();
  if (threadIdx.x == 0) flag[0] = (cnt >= 4) ? 1 : 0;
}

// ---------------------------------------------------------------------------
__global__ __launch_bounds__(256) void gn_stats_ext(const void* __restrict__ x, size_t off,
                                                    const int* __restrict__ dflag,
                                                    float* __restrict__ stats,
                                                    int cpg, int C, int N, int G) {
  int f = dflag[0];
  int b = blockIdx.x / G;
  int g = blockIdx.x % G;
  size_t base = off + ((size_t)b * C + (size_t)g * cpg) * N;
  int count = cpg * N;
  float s = 0.f, ss = 0.f;
  if (f) {
    const float* p = (const float*)x + base;
    for (int i = threadIdx.x * 4; i < count; i += 1024) {
      float4 v = *(const float4*)&p[i];
      s += v.x + v.y + v.z + v.w;
      ss += v.x * v.x + v.y * v.y + v.z * v.z + v.w * v.w;
    }
  } else {
    const short* p = (const short*)x + base;
    for (int i = threadIdx.x * 8; i < count; i += 2048) {
      bf8 v = *(const bf8*)&p[i];
#pragma unroll
      for (int j = 0; j < 8; ++j) { float t = b2f(v[j]); s += t; ss += t * t; }
    }
  }
  s = wave_sum(s);
  ss = wave_sum(ss);
  __shared__ float r1[4], r2[4];
  int wid = threadIdx.x >> 6, lane = threadIdx.x & 63;
  if (lane == 0) { r1[wid] = s; r2[wid] = ss; }
  __syncthreads();
  if (threadIdx.x == 0) {
    s = r1[0] + r1[1] + r1[2] + r1[3];
    ss = r2[0] + r2[1] + r2[2] + r2[3];
    float mean = s / (float)count;
    float var = ss / (float)count - mean * mean;
    stats[blockIdx.x * 2 + 0] = mean;
    stats[blockIdx.x * 2 + 1] = rsqrtf(fmaxf(var, 0.f) + 1e-5f);
  }
}

__global__ __launch_bounds__(256) void gn_stats2(const short* __restrict__ h1,
                                                 float* __restrict__ stats) {
  int b = blockIdx.x >> 5, g = blockIdx.x & 31;
  int nr = threadIdx.x >> 1, half = (threadIdx.x & 1) * 8;
  float s = 0.f, ss = 0.f;
  for (int n = nr; n < 1024; n += 128) {
    bf8 v = *(const bf8*)&h1[((size_t)b * 1024 + n) * 512 + g * 16 + half];
#pragma unroll
    for (int j = 0; j < 8; ++j) { float t = b2f(v[j]); s += t; ss += t * t; }
  }
  s = wave_sum(s);
  ss = wave_sum(ss);
  __shared__ float r1[4], r2[4];
  int wid = threadIdx.x >> 6, lane = threadIdx.x & 63;
  if (lane == 0) { r1[wid] = s; r2[wid] = ss; }
  __syncthreads();
  if (threadIdx.x == 0) {
    s = r1[0] + r1[1] + r1[2] + r1[3];
    ss = r2[0] + r2[1] + r2[2] + r2[3];
    float mean = s / 16384.f;
    float var = ss / 16384.f - mean * mean;
    stats[blockIdx.x * 2 + 0] = mean;
    stats[blockIdx.x * 2 + 1] = rsqrtf(fmaxf(var, 0.f) + 1e-5f);
  }
}

__global__ __launch_bounds__(256) void make_affine(const float* __restrict__ stats,
                                                   const void* __restrict__ gamma,
                                                   const void* __restrict__ beta,
                                                   const int* __restrict__ dflag,
                                                   float* __restrict__ sA, float* __restrict__ tA,
                                                   int C, int cpg, int total) {
  int f = dflag[0];
  int i = blockIdx.x * blockDim.x + threadIdx.x;
  if (i >= total) return;
  int b = i / C, c = i % C;
  int G = C / cpg;
  int g = c / cpg;
  float mean = stats[(b * G + g) * 2 + 0];
  float rstd = stats[(b * G + g) * 2 + 1];
  float gm = ldin(gamma, c, f);
  float bt = ldin(beta, c, f);
  sA[i] = rstd * gm;
  tA[i] = bt - mean * rstd * gm;
}

// ---------------------------------------------------------------------------
__global__ __launch_bounds__(256) void transpose_affine(const void* __restrict__ x, size_t xoff,
                                                        const int* __restrict__ dflag,
                                                        const float* __restrict__ stats1,
                                                        const void* __restrict__ gamma,
                                                        const void* __restrict__ beta,
                                                        short* __restrict__ xT) {
  int f = dflag[0];
  __shared__ short xs[64 * 264];
  int b = blockIdx.y, n0 = blockIdx.x * 64;
  int tid = threadIdx.x;
  int cl = tid >> 3;
  int nl8 = (tid & 7) * 8;
#pragma unroll
  for (int p = 0; p < 8; ++p) {
    int c = p * 32 + cl;
    float mean = stats1[(b * 32 + (c >> 3)) * 2 + 0];
    float rstd = stats1[(b * 32 + (c >> 3)) * 2 + 1];
    float gm = ldin(gamma, c, f);
    float bt = ldin(beta, c, f);
    float sA = rstd * gm;
    float tA = bt - mean * sA;
    size_t gidx = xoff + ((size_t)b * 256 + c) * 1024 + n0 + nl8;
    float v[8];
    if (f) {
      const float* px = (const float*)x;
      float4 a = *(const float4*)&px[gidx];
      float4 bb = *(const float4*)&px[gidx + 4];
      v[0] = a.x; v[1] = a.y; v[2] = a.z; v[3] = a.w;
      v[4] = bb.x; v[5] = bb.y; v[6] = bb.z; v[7] = bb.w;
    } else {
      bf8 a = *(const bf8*)&((const short*)x)[gidx];
#pragma unroll
      for (int j = 0; j < 8; ++j) v[j] = b2f(a[j]);
    }
#pragma unroll
    for (int j = 0; j < 8; ++j) xs[(nl8 + j) * 264 + c] = f2b(v[j] * sA + tA);
  }
  __syncthreads();
  int nl = tid >> 2, cch = (tid & 3) * 64;
#pragma unroll
  for (int m = 0; m < 8; ++m)
    *(bf8*)&xT[((size_t)b * 1024 + n0 + nl) * 256 + cch + m * 8] =
        *(const bf8*)&xs[nl * 264 + cch + m * 8];
}

__global__ __launch_bounds__(256) void affine_apply(const short* __restrict__ h1,
                                                    const float* __restrict__ s2,
                                                    const float* __restrict__ t2,
                                                    short* __restrict__ out) {
  size_t gid = (size_t)blockIdx.x * 256 + threadIdx.x;
  size_t base = gid * 8;
  int bl = (int)(base >> 19);
  int c = (int)(base & 511);
  bf8 v = *(const bf8*)&h1[base];
  bf8 o;
#pragma unroll
  for (int j = 0; j < 8; ++j)
    o[j] = f2b(b2f(v[j]) * s2[bl * 512 + c + j] + t2[bl * 512 + c + j]);
  *(bf8*)&out[base] = o;
}

// ---------------------------------------------------------------------------
// Generic MFMA GEMM (R13 version, proven): OUT[z][p][q] = scale *
// sum_k Bm[p][k]*Am[q][k]. BK=64, global_load_lds(16B) staging, 8-chunk XOR
// swizzle, 16x16x32 MFMA. Dual-weight merge: if blockIdx.y >= ysplit, use
// Am2/Out2 with p-tile index (blockIdx.y - ysplit) — merges independent
// GEMM pairs that share the B operand into one launch (kills a stream tail).
template <int A_EXT, int B_EXT, int OUT_T, int BIAS_P_, int BIAS_Q_, int RES_T>
__global__ __launch_bounds__(256) void mm(
    const void* __restrict__ Am, size_t aoff, int lda, size_t zsa,
    const void* __restrict__ Bm, size_t boff, int ldb, size_t zsb,
    void* __restrict__ Out, size_t ooff, int ldc, size_t zsc,
    const void* __restrict__ Res, size_t roff, size_t zsr, float res_scale,
    const void* __restrict__ biasP, const void* __restrict__ biasQ,
    const int* __restrict__ dflag, float scale, int P, int K,
    const void* __restrict__ Am2, void* __restrict__ Out2, int ysplit) {
  const int f = dflag[0];
  __shared__ short lA[128 * 64];
  __shared__ short lB[128 * 64];
  const int tid = threadIdx.x;
  const int z = blockIdx.z;
  int yy = blockIdx.y;
  const void* Ause = Am;
  void* Ouse = Out;
  if (yy >= ysplit) { Ause = Am2; Ouse = Out2; yy -= ysplit; }
  const int q0 = blockIdx.x * 128, p0 = yy * 128;
  const int l = tid & 63;
  const int w = tid >> 6;
  const int wq = (w & 1) * 64, wp = (w >> 1) * 64;
  const int lm = l & 15, quad = l >> 4;
  const int drow = l >> 3;
  const int gchunk = (l & 7) ^ ((l >> 3) & 7);
  const int rx = lm & 7;

  f32x4 acc[4][4];
#pragma unroll
  for (int i = 0; i < 4; ++i)
#pragma unroll
    for (int j = 0; j < 4; ++j) acc[i][j] = (f32x4){0.f, 0.f, 0.f, 0.f};

  for (int kk = 0; kk < K; kk += 64) {
    __syncthreads();
    // ---- stage A tile (rows q0..q0+127, always valid; A = Ause) ----
    if (!(A_EXT && f)) {
      const short* As = (const short*)Ause;
#pragma unroll
      for (int t = 0; t < 4; ++t) {
        int rl = w * 32 + t * 8;
        size_t g = aoff + (size_t)z * zsa + (size_t)(q0 + rl + drow) * lda + kk + gchunk * 8;
        gl_lds16(As + g, &lA[rl * 64]);
      }
    } else {
      const float* p = (const float*)Ause;
      int r = tid >> 1;
      size_t g = aoff + (size_t)z * zsa + (size_t)(q0 + r) * lda + kk;
#pragma unroll
      for (int ci = 0; ci < 4; ++ci) {
        int pc = (tid & 1) * 4 + ci;
        int gc = pc ^ (r & 7);
        short tmp[8];
#pragma unroll
        for (int i2 = 0; i2 < 8; i2 += 4) {
          float4 t4 = *(const float4*)&p[g + gc * 8 + i2];
          tmp[i2] = f2b(t4.x); tmp[i2 + 1] = f2b(t4.y);
          tmp[i2 + 2] = f2b(t4.z); tmp[i2 + 3] = f2b(t4.w);
        }
        *(bf8*)&lA[r * 64 + pc * 8] = *(bf8*)&tmp[0];
      }
    }
    // ---- stage B tile (rows p0..p0+127, guard >= P) ----
    if (!(B_EXT && f)) {
      const short* Bs = (const short*)Bm;
#pragma unroll
      for (int t = 0; t < 4; ++t) {
        int rl = w * 32 + t * 8;
        int r = rl + drow;
        if (p0 + r < P) {
          size_t g = boff + (size_t)z * zsb + (size_t)(p0 + r) * ldb + kk + gchunk * 8;
          gl_lds16(Bs + g, &lB[rl * 64]);
        }
      }
    } else {
      const float* p = (const float*)Bm;
      int r = tid >> 1;
      bool valid = (p0 + r) < P;
      size_t g = boff + (size_t)z * zsb + (size_t)(p0 + r) * ldb + kk;
#pragma unroll
      for (int ci = 0; ci < 4; ++ci) {
        int pc = (tid & 1) * 4 + ci;
        int gc = pc ^ (r & 7);
        short tmp[8] = {0, 0, 0, 0, 0, 0, 0, 0};
        if (valid) {
#pragma unroll
          for (int i2 = 0; i2 < 8; i2 += 4) {
            float4 t4 = *(const float4*)&p[g + gc * 8 + i2];
            tmp[i2] = f2b(t4.x); tmp[i2 + 1] = f2b(t4.y);
            tmp[i2 + 2] = f2b(t4.z); tmp[i2 + 3] = f2b(t4.w);
          }
        }
        *(bf8*)&lB[r * 64 + pc * 8] = *(bf8*)&tmp[0];
      }
    }
    __syncthreads();  // drains vmcnt (DMA) + lgkmcnt before reads

#pragma unroll
    for (int s = 0; s < 2; ++s) {
      bf8 af[4], bfr[4];
#pragma unroll
      for (int i = 0; i < 4; ++i)
        af[i] = *(const bf8*)&lA[(wq + i * 16 + lm) * 64 + (((s * 4 + quad) ^ rx) * 8)];
#pragma unroll
      for (int i = 0; i < 4; ++i)
        bfr[i] = *(const bf8*)&lB[(wp + i * 16 + lm) * 64 + (((s * 4 + quad) ^ rx) * 8)];
#pragma unroll
      for (int qi = 0; qi < 4; ++qi)
#pragma unroll
        for (int pi = 0; pi < 4; ++pi)
          acc[qi][pi] = __builtin_amdgcn_mfma_f32_16x16x32_bf16(af[qi], bfr[pi], acc[qi][pi], 0, 0, 0);
    }
  }

  const size_t obase = ooff + (size_t)z * zsc;
#pragma unroll
  for (int pi = 0; pi < 4; ++pi) {
    int p = p0 + wp + pi * 16 + lm;
    if (p >= P) continue;
    float bp = BIAS_P_ ? ldin(biasP, p, f) : 0.f;
#pragma unroll
    for (int qi = 0; qi < 4; ++qi) {
      int q = q0 + wq + qi * 16 + quad * 4;
      f32x4 d = acc[qi][pi];
      float v[4];
#pragma unroll
      for (int r = 0; r < 4; ++r) {
        v[r] = d[r] * scale + bp;
        if (BIAS_Q_) v[r] += ldin(biasQ, q + r, f);
      }
      if (RES_T == 1) {
        bf4 rv = *(const bf4*)&reinterpret_cast<const short*>(Res)[roff + (size_t)z * zsr + (size_t)p * ldc + q];
#pragma unroll
        for (int r = 0; r < 4; ++r) v[r] += res_scale * b2f(rv[r]);
      } else if (RES_T == 2) {
        size_t ri = roff + (size_t)z * zsr + (size_t)p * ldc + q;
        if (f) {
          float4 rf = *(const float4*)&reinterpret_cast<const float*>(Res)[ri];
          v[0] += res_scale * rf.x; v[1] += res_scale * rf.y;
          v[2] += res_scale * rf.z; v[3] += res_scale * rf.w;
        } else {
          bf4 rv = *(const bf4*)&reinterpret_cast<const short*>(Res)[ri];
#pragma unroll
          for (int r = 0; r < 4; ++r) v[r] += res_scale * b2f(rv[r]);
        }
      }
      size_t idx = obase + (size_t)p * ldc + q;
      if (OUT_T == 0) {
        bf4 o;
#pragma unroll
        for (int r = 0; r < 4; ++r) o[r] = f2b(v[r]);
        *(bf4*)&reinterpret_cast<short*>(Ouse)[idx] = o;
      } else if (OUT_T == 1) {
        f32x4 o = {v[0], v[1], v[2], v[3]};
        *(f32x4*)&reinterpret_cast<float*>(Ouse)[idx] = o;
      } else {
        if (f) {
          f32x4 o = {v[0], v[1], v[2], v[3]};
          *(f32x4*)&reinterpret_cast<float*>(Ouse)[idx] = o;
        } else {
          bf4 o;
#pragma unroll
          for (int r = 0; r < 4; ++r) o[r] = f2b(v[r]);
          *(bf4*)&reinterpret_cast<short*>(Ouse)[idx] = o;
        }
      }
    }
  }
}

// ---------------------------------------------------------------------------
// Fused flash self-attention R20: 32x32x16 MFMA, specialized waves.
// 512 threads = 8 waves. Waves 0-3 (QK): (rt=w&1 row-half, kh=w>>1 key-half).
// Waves 4-7 (PV): (rt2=w&1 row-half, dh=(w>>1)&1 dim-half).
// 64-key tiles, 16 tiles; loop t=0..16 with ONE barrier per iteration:
//   iter t: [all] DMA tile t+1 -> KL[(t+1)&1] (t<=14)
//           [QK]  S^T(t) = mfma(K,Q) 32 MFMA (2 K-passes, Q reloaded from
//                 L2 to keep aq=64 VGPR); exp; lsum; P^T -> PL[t&1] (XOR swz)
//           [PV]  O^T(t-1) += mfma(V^T from L2, P^T from PL[(t-1)&1]) 32 MFMA
//           barrier
// 32x32x16 layouts: A row=l&31,k=(l>>5)*8+e; B col=l&31 same k;
// C/D col=l&31, row(reg)= (reg&3)+8*(reg>>2)+4*(l>>5)   [m74/m101].
// S^T[key][qrow]: lane holds qrow=l&31, 16 keys in regs -> exp/rowsum local.
// Epilogue: O^T -> O via LDS transpose in dead KL space; deferred 1/lsum.
__global__ __launch_bounds__(512, 1) void flash_attn(const short* __restrict__ Q,
                                                     const short* __restrict__ Kb,
                                                     const short* __restrict__ VT,
                                                     short* __restrict__ O,
                                                     float scale, int NBm1) {
  __shared__ short KL[2][64 * 512];  // [buf][c=dim/8][key 0..63][8] = 64 KB
  __shared__ short PL[2][64 * 64];   // [buf][qrow][key] XOR-swizzled 16B blks
  __shared__ float LS[2][64];        // [key-half][qrow] partial sums
  const int lin = blockIdx.x;
  const int b = lin & NBm1;
  const int i0 = (lin >> (31 - __builtin_clz(NBm1 + 1))) * 64;
  const int tid = threadIdx.x;
  const int w = tid >> 6, l = tid & 63;
  const int l31 = l & 31, lh = l >> 5;
  const bool isQK = w < 4;

  const short* kbase = Kb + (size_t)b * 524288;
  const short* vbase = VT + (size_t)b * 524288;

  // QK wave identity
  const int rt = w & 1, kh = (w >> 1) & 1;
  // PV wave identity
  const int rt2 = w & 1, dh = (w >> 1) & 1;

  f32x16 sacc;            // QK: S^T tile (16 regs)
  f32x16 oacc[8];         // PV: O^T 8 dim-tiles x 32 qrows (128 acc regs)
  float lsum = 0.f;       // QK: per-lane row-sum (qrow = l31, key subset lh)
#pragma unroll
  for (int i = 0; i < 8; ++i) oacc[i] = (f32x16)(0.f);

  // prologue DMA: tile 0 -> KL[0]; wave w stages chunk-rows w*8..w*8+7
  // (one instr: 64 lanes x 16B = one full [key][8] row of chunk c).
#pragma unroll
  for (int i = 0; i < 8; ++i) {
    int c = w * 8 + i;
    gl_lds16(kbase + (size_t)l * 512 + c * 8, &KL[0][c * 512]);
  }
  __syncthreads();

  for (int t = 0; t <= 16; ++t) {
    const int p = t & 1;
    if (t <= 14) {  // DMA tile t+1 (keys (t+1)*64 ..) into KL[p^1]
#pragma unroll
      for (int i = 0; i < 8; ++i) {
        int c = w * 8 + i;
        gl_lds16(kbase + (size_t)((t + 1) * 64 + l) * 512 + c * 8, &KL[p ^ 1][c * 512]);
      }
    }

    if (isQK) {
      if (t <= 15) {
        const int j0 = t * 64;
        // ---- S^T(t) = K(32 keys) x Q^T(32 rows), K=512 in 2 passes ----
        sacc = (f32x16)(0.f);
        const short* qrow_p = Q + ((size_t)b * 1024 + i0 + rt * 32 + l31) * 512;
#pragma unroll
        for (int h = 0; h < 2; ++h) {
          bf8 aq[8];
#pragma unroll
          for (int kc = 0; kc < 8; ++kc)
            aq[kc] = *(const bf8*)&qrow_p[h * 256 + (kc * 2 + lh) * 8 + ((kc & 1) ? 0 : 0)];
          // NOTE: k = h*256 + kc*32?? — see loop below; aq[kc] covers
          // k = h*256 + kc*32 + lh*... careful: each MFMA K=16, frag k-elems
          // (lh)*8+e. Two MFMAs per 32-k block. Load per-MFMA instead:
          (void)aq;
          __builtin_amdgcn_s_setprio(1);
#pragma unroll
          for (int kc = 0; kc < 16; ++kc) {
            // k-chunk K=16: global k0 = h*256 + kc*16 + lh*8
            bf8 qf = *(const bf8*)&qrow_p[h * 256 + kc * 16 + lh * 8];
            int c = h * 32 + kc * 2 + lh;
            bf8 kf = *(const bf8*)&KL[p][c * 512 + (kh * 32 + l31) * 8];
            sacc = __builtin_amdgcn_mfma_f32_32x32x16_bf16(kf, qf, sacc, 0, 0, 0);
          }
          __builtin_amdgcn_s_setprio(0);
        }
        // ---- exp + lane-local row-sum + P^T -> PL[p] (swizzled) ----
#pragma unroll
        for (int r = 0; r < 16; ++r) {
          float e = __expf(sacc[r] * scale);
          lsum += e;
          int keyL = kh * 32 + (r & 3) + 8 * (r >> 2) + 4 * lh;  // 0..63
          int blk = (keyL >> 3) ^ (l31 & 7);
          PL[p][l31 * 64 + rt * 0 + 0 + blk * 8 + (keyL & 7) + (rt ? 32 * 64 : 0)] = f2b(e);
        }
      } else {
        // t == 16: fold lsum across key-subsets and publish
        lsum += __shfl_xor(lsum, 32);
        if (lh == 0) LS[kh][rt * 32 + l31] = lsum;
      }
    } else {
      if (t >= 1) {
        const int tp = t - 1, pb = (t - 1) & 1;
        const int j0 = tp * 64;
        // ---- O^T(tp) += V^T x P^T : 8 dim-tiles x 4 k-chunks ----
        __builtin_amdgcn_s_setprio(1);
#pragma unroll
        for (int kc = 0; kc < 4; ++kc) {
          // B-frag: P^T rows rt2*32.., keys kc*16 + lh*8 ..
          int qrowL = rt2 * 32 + l31;
          int blk = (kc * 2 + lh) ^ (l31 & 7);
          bf8 pf = *(const bf8*)&PL[pb][(qrowL & 31) * 64 + blk * 8 + (rt2 ? 32 * 64 : 0)];
#pragma unroll
          for (int dt = 0; dt < 8; ++dt) {
            bf8 vf = *(const bf8*)&vbase[(size_t)(dh * 256 + dt * 32 + l31) * 1024 + j0 + kc * 16 + lh * 8];
            oacc[dt] = __builtin_amdgcn_mfma_f32_32x32x16_bf16(vf, pf, oacc[dt], 0, 0, 0);
          }
        }
        __builtin_amdgcn_s_setprio(0);
      }
    }
    __syncthreads();
  }

  // ---- PV epilogue: normalize + O^T -> O transpose through dead KL ----
  if (!isQK) {
    int row = rt2 * 32 + l31;
    float inv = 1.f / (LS[0][row] + LS[1][row]);
    short* scratch = &KL[0][0] + (size_t)(w - 4) * 32 * 264;
#pragma unroll
    for (int dt = 0; dt < 8; ++dt)
#pragma unroll
      for (int r = 0; r < 16; ++r) {
        int dimL = dt * 32 + (r & 3) + 8 * (r >> 2) + 4 * lh;
        scratch[l31 * 264 + dimL] = f2b(oacc[dt][r] * inv);
      }
    // same-wave RAW through LDS: compiler inserts lgkmcnt waits.
    short* ob = O + ((size_t)b * 1024 + i0 + rt2 * 32 + l31) * 512 + dh * 256 + lh * 128;
#pragma unroll
    for (int i = 0; i < 16; ++i)
      *(bf8*)&ob[i * 8] = *(const bf8*)&scratch[l31 * 264 + lh * 128 + i * 8];
  }
}

// ---------------------------------------------------------------------------
// Fused cross-attention via MFMA (unchanged).
__global__ __launch_bounds__(256) void cross_attn_mfma(const short* __restrict__ q2,
                                                       const short* __restrict__ k2,
                                                       const short* __restrict__ v2,
                                                       short* __restrict__ o2) {
  __shared__ short Pl[64 * 104];
  __shared__ short VTl[64 * 104];
  const int b = blockIdx.z, h = blockIdx.y, i0 = blockIdx.x * 64;
  const int tid = threadIdx.x;
  const int w = tid >> 6, l = tid & 63, lm = l & 15, quad = l >> 4;

  for (int idx = tid; idx < 64 * 104 / 4; idx += 256)
    *(bf4*)&VTl[idx * 4] = (bf4){0, 0, 0, 0};
  __syncthreads();
  for (int idx = tid; idx < 77 * 64; idx += 256) {
    int j = idx >> 6, d = idx & 63;
    VTl[d * 104 + j] = v2[(size_t)b * 39424 + j * 512 + h * 64 + d];
  }

  const short* qb = q2 + ((size_t)b * 1024 + i0 + w * 16 + lm) * 512 + h * 64;
  bf8 aq0 = *(const bf8*)&qb[quad * 8];
  bf8 aq1 = *(const bf8*)&qb[32 + quad * 8];
  const short* kb = k2 + (size_t)b * 39424 + h * 64;
  f32x4 sacc[5];
#pragma unroll
  for (int jt = 0; jt < 5; ++jt) sacc[jt] = (f32x4){0.f, 0.f, 0.f, 0.f};
#pragma unroll
  for (int jt = 0; jt < 5; ++jt) {
    int j = jt * 16 + lm;
    bf8 b0 = {0, 0, 0, 0, 0, 0, 0, 0}, b1 = {0, 0, 0, 0, 0, 0, 0, 0};
    if (j < 77) {
      b0 = *(const bf8*)&kb[j * 512 + quad * 8];
      b1 = *(const bf8*)&kb[j * 512 + 32 + quad * 8];
    }
    sacc[jt] = __builtin_amdgcn_mfma_f32_16x16x32_bf16(aq0, b0, sacc[jt], 0, 0, 0);
    sacc[jt] = __builtin_amdgcn_mfma_f32_16x16x32_bf16(aq1, b1, sacc[jt], 0, 0, 0);
  }
#pragma unroll
  for (int jt = 0; jt < 5; ++jt) {
    bool valid = (jt * 16 + lm) < 77;
#pragma unroll
    for (int r = 0; r < 4; ++r)
      sacc[jt][r] = valid ? sacc[jt][r] * 0.125f : -1e30f;
  }
#pragma unroll
  for (int r = 0; r < 4; ++r) {
    float mx = sacc[0][r];
#pragma unroll
    for (int jt = 1; jt < 5; ++jt) mx = fmaxf(mx, sacc[jt][r]);
    mx = fmaxf(mx, __shfl_xor(mx, 1));
    mx = fmaxf(mx, __shfl_xor(mx, 2));
    mx = fmaxf(mx, __shfl_xor(mx, 4));
    mx = fmaxf(mx, __shfl_xor(mx, 8));
    float s = 0.f;
    float e[5];
#pragma unroll
    for (int jt = 0; jt < 5; ++jt) { e[jt] = __expf(sacc[jt][r] - mx); s += e[jt]; }
    s += __shfl_xor(s, 1);
    s += __shfl_xor(s, 2);
    s += __shfl_xor(s, 4);
    s += __shfl_xor(s, 8);
    float iv = 1.f / s;
    int row = w * 16 + quad * 4 + r;
#pragma unroll
    for (int jt = 0; jt < 5; ++jt) Pl[row * 104 + jt * 16 + lm] = f2b(e[jt] * iv);
  }
#pragma unroll
  for (int r = 0; r < 4; ++r) Pl[(w * 16 + quad * 4 + r) * 104 + 80 + lm] = 0;
  __syncthreads();

  f32x4 oacc[4];
#pragma unroll
  for (int dt = 0; dt < 4; ++dt) oacc[dt] = (f32x4){0.f, 0.f, 0.f, 0.f};
#pragma unroll
  for (int kc = 0; kc < 3; ++kc) {
    bf8 ap = *(const bf8*)&Pl[(w * 16 + lm) * 104 + kc * 32 + quad * 8];
#pragma unroll
    for (int dt = 0; dt < 4; ++dt) {
      bf8 bv = *(const bf8*)&VTl[(dt * 16 + lm) * 104 + kc * 32 + quad * 8];
      oacc[dt] = __builtin_amdgcn_mfma_f32_16x16x32_bf16(ap, bv, oacc[dt], 0, 0, 0);
    }
  }
  short* ob = o2 + ((size_t)b * 1024 + i0 + w * 16 + quad * 4) * 512 + h * 64;
#pragma unroll
  for (int dt = 0; dt < 4; ++dt)
#pragma unroll
    for (int r = 0; r < 4; ++r)
      ob[(size_t)r * 512 + dt * 16 + lm] = f2b(oacc[dt][r]);
}

// ---------------------------------------------------------------------------
extern "C" void kernel_launch(void* const* d_in, const int* in_sizes, int n_in,
                              void* d_out, int out_size, void* d_ws, size_t ws_size,
                              hipStream_t stream) {
  const void* x       = d_in[0];
  const void* ctx     = d_in[1];
  const void* gn1_g   = d_in[2];
  const void* gn1_b   = d_in[3];
  const void* w_in    = d_in[4];
  const void* b_in    = d_in[5];
  const void* sa_wk   = d_in[6];
  const void* sa_wq   = d_in[7];
  const void* sa_wv   = d_in[8];
  const void* sa_wp   = d_in[9];
  const void* sa_gn_g = d_in[10];
  const void* sa_gn_b = d_in[11];
  const void* ca_wq   = d_in[12];
  const void* ca_wk   = d_in[13];
  const void* ca_wv   = d_in[14];
  const void* ca_wo   = d_in[15];
  const void* ca_bo   = d_in[16];
  const void* w_out   = d_in[17];
  const void* b_out   = d_in[18];

  const int B = 16;
  int NB = 16;
  while (NB > 1 && 131072ull + (size_t)NB * 5767168ull > ws_size) NB >>= 1;

  char* base = reinterpret_cast<char*>(d_ws);
  int* flagp = reinterpret_cast<int*>(base);
  float* smf = reinterpret_cast<float*>(base + 1024);
  float* stats1 = smf;
  float* stats2 = smf + 1024;
  float* s2 = smf + 10240;
  float* t2 = smf + 18432;
  char* big = base + 131072;
  const size_t MB = 1048576;
  short* U0 = (short*)(big + 0 * (size_t)NB * MB);
  short* U1 = (short*)(big + 1 * (size_t)NB * MB);
  short* U2 = (short*)(big + 2 * (size_t)NB * MB);
  short* U3 = (short*)(big + 3 * (size_t)NB * MB);
  short* U4 = (short*)(big + 4 * (size_t)NB * MB);
  char* Sreg = big + 5 * (size_t)NB * MB;
  short* xT = (short*)Sreg;
  short* k2 = (short*)Sreg;
  short* v2 = (short*)(Sreg + (size_t)NB * 78848);

  probe_dtype<<<1, 256, 0, stream>>>((const unsigned short*)x, flagp);

  const float qk_scale = 0.044194173824159216f;
  const int NOSPLIT = 1 << 30;

  for (int b0 = 0; b0 < B; b0 += NB) {
    size_t xoff = (size_t)b0 * 262144;
    size_t coff = (size_t)b0 * 59136;

    gn_stats_ext<<<NB * 32, 256, 0, stream>>>(x, xoff, flagp, stats1, 8, 256, 1024, 32);
    transpose_affine<<<dim3(16, NB), 256, 0, stream>>>(x, xoff, flagp, stats1, gn1_g, gn1_b, xT);
    mm<1, 0, 0, 0, 1, 0><<<dim3(4, 8, NB), 256, 0, stream>>>(
        w_in, 0, 256, 0, xT, 0, 256, 262144, U0, 0, 512, 524288,
        nullptr, 0, 0, 0.f, nullptr, b_in, flagp, 1.f, 1024, 256,
        w_in, U0, NOSPLIT);

    gn_stats2<<<NB * 32, 256, 0, stream>>>(U0, stats2);
    make_affine<<<(NB * 512 + 255) / 256, 256, 0, stream>>>(stats2, sa_gn_g, sa_gn_b, flagp, s2, t2, 512, 16, NB * 512);
    affine_apply<<<NB * 256, 256, 0, stream>>>(U0, s2, t2, U1);

    // q + k merged (independent, share B operand U1): y<8 -> q(U2), y>=8 -> k(U3)
    mm<1, 0, 0, 0, 0, 0><<<dim3(4, 16, NB), 256, 0, stream>>>(
        sa_wq, 0, 512, 0, U1, 0, 512, 524288, U2, 0, 512, 524288,
        nullptr, 0, 0, 0.f, nullptr, nullptr, flagp, 1.f, 1024, 512,
        sa_wk, U3, 8);
    mm<0, 1, 0, 0, 0, 0><<<dim3(8, 4, NB), 256, 0, stream>>>(
        U1, 0, 512, 524288, sa_wv, 0, 512, 0, U4, 0, 1024, 524288,
        nullptr, 0, 0, 0.f, nullptr, nullptr, flagp, 1.f, 512, 512,
        U1, U4, NOSPLIT);

    flash_attn<<<dim3(16 * NB), 512, 0, stream>>>(U2, U3, U4, U1, qk_scale, NB - 1);

    mm<1, 0, 0, 0, 0, 1><<<dim3(4, 8, NB), 256, 0, stream>>>(
        sa_wp, 0, 512, 0, U1, 0, 512, 524288, U3, 0, 512, 524288,
        U0, 0, 524288, 2.f, nullptr, nullptr, flagp, 1.f, 1024, 512,
        sa_wp, U3, NOSPLIT);

    mm<1, 0, 0, 0, 0, 0><<<dim3(4, 8, NB), 256, 0, stream>>>(
        ca_wq, 0, 512, 0, U3, 0, 512, 524288, U2, 0, 512, 524288,
        nullptr, 0, 0, 0.f, nullptr, nullptr, flagp, 1.f, 1024, 512,
        ca_wq, U2, NOSPLIT);
    // ca_wk + ca_wv merged (independent, share B operand ctx): y=0 -> k2, y=1 -> v2
    mm<1, 1, 0, 0, 0, 0><<<dim3(4, 2, NB), 256, 0, stream>>>(
        ca_wk, 0, 768, 0, ctx, coff, 768, 59136, k2, 0, 512, 39424,
        nullptr, 0, 0, 0.f, nullptr, nullptr, flagp, 1.f, 77, 768,
        ca_wv, v2, 1);
    cross_attn_mfma<<<dim3(16, 8, NB), 256, 0, stream>>>(U2, k2, v2, U4);

    mm<1, 0, 0, 0, 1, 1><<<dim3(4, 8, NB), 256, 0, stream>>>(
        ca_wo, 0, 512, 0, U4, 0, 512, 524288, U0, 0, 512, 524288,
        U3, 0, 524288, 1.f, nullptr, ca_bo, flagp, 1.f, 1024, 512,
        ca_wo, U0, NOSPLIT);

    mm<0, 1, 2, 1, 0, 2><<<dim3(8, 2, NB), 256, 0, stream>>>(
        U0, 0, 512, 524288, w_out, 0, 512, 0, d_out, xoff, 1024, 262144,
        x, xoff, 262144, 1.f, b_out, nullptr, flagp, 1.f, 256, 512,
        U0, d_out, NOSPLIT);
  }

  (void)in_sizes; (void)n_in; (void)out_size;
}

// Round 9
// 587.055 us; speedup vs baseline: 1.0881x; 1.0220x over previous
//
#include <hip/hip_runtime.h>
#include <math.h>

#define DEV __device__ __forceinline__

using f32x4 = __attribute__((ext_vector_type(4))) float;
using bf8   = __attribute__((ext_vector_type(8))) short;
using bf4   = __attribute__((ext_vector_type(4))) short;

// B=16, CIN=256, N=1024, INNER=512, CTX_N=77, CTX_D=768, HEADS=8, DH=64.
// Seq-major [n][c] bf16 activations; every GEMM is C=A*B^T with K contiguous.
// Self-attention R21: R18's exact per-wave math (wr/wj split, KL chunk-major
// DMA dbuf, PL dbuf, 2-chain QK, ONE barrier/iter) with two measured cost
// terms removed:
//   * VL deleted — PV B-frags straight from global VT[dim][key] (L2-resident;
//     R15-proven addressing). Kills 128 bv LDS reads + VL writes per iter.
//   * 256-thread blocks (4 waves, 32 rows), grid 512 -> 2 blocks/CU: the
//     exposed barrier drains (the R17/R18 floor) overlap across blocks.
// mm: R13's proven version (16x16x32, BK=64, global_load_lds(16B), XOR
// swizzle) + dual-weight merge (independent GEMM pairs in one launch).

DEV short f2b(float x) {
  unsigned u = __builtin_bit_cast(unsigned, x);
  u += 0x7FFFu + ((u >> 16) & 1u);
  return (short)(u >> 16);
}
DEV float b2f(short s) {
  unsigned u = ((unsigned)(unsigned short)s) << 16;
  return __builtin_bit_cast(float, u);
}
DEV float ldin(const void* p, size_t i, int f) {
  return f ? reinterpret_cast<const float*>(p)[i]
           : b2f(reinterpret_cast<const short*>(p)[i]);
}

typedef const __attribute__((address_space(1))) void* gas_t;
typedef __attribute__((address_space(3))) void* las_t;
DEV void gl_lds16(const short* g, short* l) {
  __builtin_amdgcn_global_load_lds((gas_t)g, (las_t)l, 16, 0, 0);
}

DEV float wave_sum(float v) {
#pragma unroll
  for (int off = 32; off > 0; off >>= 1) v += __shfl_xor(v, off);
  return v;
}

// ---------------------------------------------------------------------------
__global__ __launch_bounds__(256) void probe_dtype(const unsigned short* __restrict__ x,
                                                   int* __restrict__ flag) {
  __shared__ int cnt;
  if (threadIdx.x == 0) cnt = 0;
  __syncthreads();
  int c = 0;
  for (int i = threadIdx.x; i < 8192; i += 256) {
    int e = (x[i] >> 7) & 0xFF;
    if (e == 0xFF || e == 0x00) ++c;
  }
  atomicAdd(&cnt, c);
  __syncthreads();
  if (threadIdx.x == 0) flag[0] = (cnt >= 4) ? 1 : 0;
}

// ---------------------------------------------------------------------------
__global__ __launch_bounds__(256) void gn_stats_ext(const void* __restrict__ x, size_t off,
                                                    const int* __restrict__ dflag,
                                                    float* __restrict__ stats,
                                                    int cpg, int C, int N, int G) {
  int f = dflag[0];
  int b = blockIdx.x / G;
  int g = blockIdx.x % G;
  size_t base = off + ((size_t)b * C + (size_t)g * cpg) * N;
  int count = cpg * N;
  float s = 0.f, ss = 0.f;
  if (f) {
    const float* p = (const float*)x + base;
    for (int i = threadIdx.x * 4; i < count; i += 1024) {
      float4 v = *(const float4*)&p[i];
      s += v.x + v.y + v.z + v.w;
      ss += v.x * v.x + v.y * v.y + v.z * v.z + v.w * v.w;
    }
  } else {
    const short* p = (const short*)x + base;
    for (int i = threadIdx.x * 8; i < count; i += 2048) {
      bf8 v = *(const bf8*)&p[i];
#pragma unroll
      for (int j = 0; j < 8; ++j) { float t = b2f(v[j]); s += t; ss += t * t; }
    }
  }
  s = wave_sum(s);
  ss = wave_sum(ss);
  __shared__ float r1[4], r2[4];
  int wid = threadIdx.x >> 6, lane = threadIdx.x & 63;
  if (lane == 0) { r1[wid] = s; r2[wid] = ss; }
  __syncthreads();
  if (threadIdx.x == 0) {
    s = r1[0] + r1[1] + r1[2] + r1[3];
    ss = r2[0] + r2[1] + r2[2] + r2[3];
    float mean = s / (float)count;
    float var = ss / (float)count - mean * mean;
    stats[blockIdx.x * 2 + 0] = mean;
    stats[blockIdx.x * 2 + 1] = rsqrtf(fmaxf(var, 0.f) + 1e-5f);
  }
}

__global__ __launch_bounds__(256) void gn_stats2(const short* __restrict__ h1,
                                                 float* __restrict__ stats) {
  int b = blockIdx.x >> 5, g = blockIdx.x & 31;
  int nr = threadIdx.x >> 1, half = (threadIdx.x & 1) * 8;
  float s = 0.f, ss = 0.f;
  for (int n = nr; n < 1024; n += 128) {
    bf8 v = *(const bf8*)&h1[((size_t)b * 1024 + n) * 512 + g * 16 + half];
#pragma unroll
    for (int j = 0; j < 8; ++j) { float t = b2f(v[j]); s += t; ss += t * t; }
  }
  s = wave_sum(s);
  ss = wave_sum(ss);
  __shared__ float r1[4], r2[4];
  int wid = threadIdx.x >> 6, lane = threadIdx.x & 63;
  if (lane == 0) { r1[wid] = s; r2[wid] = ss; }
  __syncthreads();
  if (threadIdx.x == 0) {
    s = r1[0] + r1[1] + r1[2] + r1[3];
    ss = r2[0] + r2[1] + r2[2] + r2[3];
    float mean = s / 16384.f;
    float var = ss / 16384.f - mean * mean;
    stats[blockIdx.x * 2 + 0] = mean;
    stats[blockIdx.x * 2 + 1] = rsqrtf(fmaxf(var, 0.f) + 1e-5f);
  }
}

__global__ __launch_bounds__(256) void make_affine(const float* __restrict__ stats,
                                                   const void* __restrict__ gamma,
                                                   const void* __restrict__ beta,
                                                   const int* __restrict__ dflag,
                                                   float* __restrict__ sA, float* __restrict__ tA,
                                                   int C, int cpg, int total) {
  int f = dflag[0];
  int i = blockIdx.x * blockDim.x + threadIdx.x;
  if (i >= total) return;
  int b = i / C, c = i % C;
  int G = C / cpg;
  int g = c / cpg;
  float mean = stats[(b * G + g) * 2 + 0];
  float rstd = stats[(b * G + g) * 2 + 1];
  float gm = ldin(gamma, c, f);
  float bt = ldin(beta, c, f);
  sA[i] = rstd * gm;
  tA[i] = bt - mean * rstd * gm;
}

// ---------------------------------------------------------------------------
__global__ __launch_bounds__(256) void transpose_affine(const void* __restrict__ x, size_t xoff,
                                                        const int* __restrict__ dflag,
                                                        const float* __restrict__ stats1,
                                                        const void* __restrict__ gamma,
                                                        const void* __restrict__ beta,
                                                        short* __restrict__ xT) {
  int f = dflag[0];
  __shared__ short xs[64 * 264];
  int b = blockIdx.y, n0 = blockIdx.x * 64;
  int tid = threadIdx.x;
  int cl = tid >> 3;
  int nl8 = (tid & 7) * 8;
#pragma unroll
  for (int p = 0; p < 8; ++p) {
    int c = p * 32 + cl;
    float mean = stats1[(b * 32 + (c >> 3)) * 2 + 0];
    float rstd = stats1[(b * 32 + (c >> 3)) * 2 + 1];
    float gm = ldin(gamma, c, f);
    float bt = ldin(beta, c, f);
    float sA = rstd * gm;
    float tA = bt - mean * sA;
    size_t gidx = xoff + ((size_t)b * 256 + c) * 1024 + n0 + nl8;
    float v[8];
    if (f) {
      const float* px = (const float*)x;
      float4 a = *(const float4*)&px[gidx];
      float4 bb = *(const float4*)&px[gidx + 4];
      v[0] = a.x; v[1] = a.y; v[2] = a.z; v[3] = a.w;
      v[4] = bb.x; v[5] = bb.y; v[6] = bb.z; v[7] = bb.w;
    } else {
      bf8 a = *(const bf8*)&((const short*)x)[gidx];
#pragma unroll
      for (int j = 0; j < 8; ++j) v[j] = b2f(a[j]);
    }
#pragma unroll
    for (int j = 0; j < 8; ++j) xs[(nl8 + j) * 264 + c] = f2b(v[j] * sA + tA);
  }
  __syncthreads();
  int nl = tid >> 2, cch = (tid & 3) * 64;
#pragma unroll
  for (int m = 0; m < 8; ++m)
    *(bf8*)&xT[((size_t)b * 1024 + n0 + nl) * 256 + cch + m * 8] =
        *(const bf8*)&xs[nl * 264 + cch + m * 8];
}

__global__ __launch_bounds__(256) void affine_apply(const short* __restrict__ h1,
                                                    const float* __restrict__ s2,
                                                    const float* __restrict__ t2,
                                                    short* __restrict__ out) {
  size_t gid = (size_t)blockIdx.x * 256 + threadIdx.x;
  size_t base = gid * 8;
  int bl = (int)(base >> 19);
  int c = (int)(base & 511);
  bf8 v = *(const bf8*)&h1[base];
  bf8 o;
#pragma unroll
  for (int j = 0; j < 8; ++j)
    o[j] = f2b(b2f(v[j]) * s2[bl * 512 + c + j] + t2[bl * 512 + c + j]);
  *(bf8*)&out[base] = o;
}

// ---------------------------------------------------------------------------
// Generic MFMA GEMM (R13 version, proven): OUT[z][p][q] = scale *
// sum_k Bm[p][k]*Am[q][k]. BK=64, global_load_lds(16B) staging, 8-chunk XOR
// swizzle, 16x16x32 MFMA. Dual-weight merge: if blockIdx.y >= ysplit, use
// Am2/Out2 with p-tile index (blockIdx.y - ysplit) — merges independent
// GEMM pairs that share the B operand into one launch (kills a stream tail).
template <int A_EXT, int B_EXT, int OUT_T, int BIAS_P_, int BIAS_Q_, int RES_T>
__global__ __launch_bounds__(256) void mm(
    const void* __restrict__ Am, size_t aoff, int lda, size_t zsa,
    const void* __restrict__ Bm, size_t boff, int ldb, size_t zsb,
    void* __restrict__ Out, size_t ooff, int ldc, size_t zsc,
    const void* __restrict__ Res, size_t roff, size_t zsr, float res_scale,
    const void* __restrict__ biasP, const void* __restrict__ biasQ,
    const int* __restrict__ dflag, float scale, int P, int K,
    const void* __restrict__ Am2, void* __restrict__ Out2, int ysplit) {
  const int f = dflag[0];
  __shared__ short lA[128 * 64];
  __shared__ short lB[128 * 64];
  const int tid = threadIdx.x;
  const int z = blockIdx.z;
  int yy = blockIdx.y;
  const void* Ause = Am;
  void* Ouse = Out;
  if (yy >= ysplit) { Ause = Am2; Ouse = Out2; yy -= ysplit; }
  const int q0 = blockIdx.x * 128, p0 = yy * 128;
  const int l = tid & 63;
  const int w = tid >> 6;
  const int wq = (w & 1) * 64, wp = (w >> 1) * 64;
  const int lm = l & 15, quad = l >> 4;
  const int drow = l >> 3;
  const int gchunk = (l & 7) ^ ((l >> 3) & 7);
  const int rx = lm & 7;

  f32x4 acc[4][4];
#pragma unroll
  for (int i = 0; i < 4; ++i)
#pragma unroll
    for (int j = 0; j < 4; ++j) acc[i][j] = (f32x4){0.f, 0.f, 0.f, 0.f};

  for (int kk = 0; kk < K; kk += 64) {
    __syncthreads();
    // ---- stage A tile (rows q0..q0+127, always valid; A = Ause) ----
    if (!(A_EXT && f)) {
      const short* As = (const short*)Ause;
#pragma unroll
      for (int t = 0; t < 4; ++t) {
        int rl = w * 32 + t * 8;
        size_t g = aoff + (size_t)z * zsa + (size_t)(q0 + rl + drow) * lda + kk + gchunk * 8;
        gl_lds16(As + g, &lA[rl * 64]);
      }
    } else {
      const float* p = (const float*)Ause;
      int r = tid >> 1;
      size_t g = aoff + (size_t)z * zsa + (size_t)(q0 + r) * lda + kk;
#pragma unroll
      for (int ci = 0; ci < 4; ++ci) {
        int pc = (tid & 1) * 4 + ci;
        int gc = pc ^ (r & 7);
        short tmp[8];
#pragma unroll
        for (int i2 = 0; i2 < 8; i2 += 4) {
          float4 t4 = *(const float4*)&p[g + gc * 8 + i2];
          tmp[i2] = f2b(t4.x); tmp[i2 + 1] = f2b(t4.y);
          tmp[i2 + 2] = f2b(t4.z); tmp[i2 + 3] = f2b(t4.w);
        }
        *(bf8*)&lA[r * 64 + pc * 8] = *(bf8*)&tmp[0];
      }
    }
    // ---- stage B tile (rows p0..p0+127, guard >= P) ----
    if (!(B_EXT && f)) {
      const short* Bs = (const short*)Bm;
#pragma unroll
      for (int t = 0; t < 4; ++t) {
        int rl = w * 32 + t * 8;
        int r = rl + drow;
        if (p0 + r < P) {
          size_t g = boff + (size_t)z * zsb + (size_t)(p0 + r) * ldb + kk + gchunk * 8;
          gl_lds16(Bs + g, &lB[rl * 64]);
        }
      }
    } else {
      const float* p = (const float*)Bm;
      int r = tid >> 1;
      bool valid = (p0 + r) < P;
      size_t g = boff + (size_t)z * zsb + (size_t)(p0 + r) * ldb + kk;
#pragma unroll
      for (int ci = 0; ci < 4; ++ci) {
        int pc = (tid & 1) * 4 + ci;
        int gc = pc ^ (r & 7);
        short tmp[8] = {0, 0, 0, 0, 0, 0, 0, 0};
        if (valid) {
#pragma unroll
          for (int i2 = 0; i2 < 8; i2 += 4) {
            float4 t4 = *(const float4*)&p[g + gc * 8 + i2];
            tmp[i2] = f2b(t4.x); tmp[i2 + 1] = f2b(t4.y);
            tmp[i2 + 2] = f2b(t4.z); tmp[i2 + 3] = f2b(t4.w);
          }
        }
        *(bf8*)&lB[r * 64 + pc * 8] = *(bf8*)&tmp[0];
      }
    }
    __syncthreads();  // drains vmcnt (DMA) + lgkmcnt before reads

#pragma unroll
    for (int s = 0; s < 2; ++s) {
      bf8 af[4], bfr[4];
#pragma unroll
      for (int i = 0; i < 4; ++i)
        af[i] = *(const bf8*)&lA[(wq + i * 16 + lm) * 64 + (((s * 4 + quad) ^ rx) * 8)];
#pragma unroll
      for (int i = 0; i < 4; ++i)
        bfr[i] = *(const bf8*)&lB[(wp + i * 16 + lm) * 64 + (((s * 4 + quad) ^ rx) * 8)];
#pragma unroll
      for (int qi = 0; qi < 4; ++qi)
#pragma unroll
        for (int pi = 0; pi < 4; ++pi)
          acc[qi][pi] = __builtin_amdgcn_mfma_f32_16x16x32_bf16(af[qi], bfr[pi], acc[qi][pi], 0, 0, 0);
    }
  }

  const size_t obase = ooff + (size_t)z * zsc;
#pragma unroll
  for (int pi = 0; pi < 4; ++pi) {
    int p = p0 + wp + pi * 16 + lm;
    if (p >= P) continue;
    float bp = BIAS_P_ ? ldin(biasP, p, f) : 0.f;
#pragma unroll
    for (int qi = 0; qi < 4; ++qi) {
      int q = q0 + wq + qi * 16 + quad * 4;
      f32x4 d = acc[qi][pi];
      float v[4];
#pragma unroll
      for (int r = 0; r < 4; ++r) {
        v[r] = d[r] * scale + bp;
        if (BIAS_Q_) v[r] += ldin(biasQ, q + r, f);
      }
      if (RES_T == 1) {
        bf4 rv = *(const bf4*)&reinterpret_cast<const short*>(Res)[roff + (size_t)z * zsr + (size_t)p * ldc + q];
#pragma unroll
        for (int r = 0; r < 4; ++r) v[r] += res_scale * b2f(rv[r]);
      } else if (RES_T == 2) {
        size_t ri = roff + (size_t)z * zsr + (size_t)p * ldc + q;
        if (f) {
          float4 rf = *(const float4*)&reinterpret_cast<const float*>(Res)[ri];
          v[0] += res_scale * rf.x; v[1] += res_scale * rf.y;
          v[2] += res_scale * rf.z; v[3] += res_scale * rf.w;
        } else {
          bf4 rv = *(const bf4*)&reinterpret_cast<const short*>(Res)[ri];
#pragma unroll
          for (int r = 0; r < 4; ++r) v[r] += res_scale * b2f(rv[r]);
        }
      }
      size_t idx = obase + (size_t)p * ldc + q;
      if (OUT_T == 0) {
        bf4 o;
#pragma unroll
        for (int r = 0; r < 4; ++r) o[r] = f2b(v[r]);
        *(bf4*)&reinterpret_cast<short*>(Ouse)[idx] = o;
      } else if (OUT_T == 1) {
        f32x4 o = {v[0], v[1], v[2], v[3]};
        *(f32x4*)&reinterpret_cast<float*>(Ouse)[idx] = o;
      } else {
        if (f) {
          f32x4 o = {v[0], v[1], v[2], v[3]};
          *(f32x4*)&reinterpret_cast<float*>(Ouse)[idx] = o;
        } else {
          bf4 o;
#pragma unroll
          for (int r = 0; r < 4; ++r) o[r] = f2b(v[r]);
          *(bf4*)&reinterpret_cast<short*>(Ouse)[idx] = o;
        }
      }
    }
  }
}

// ---------------------------------------------------------------------------
// Fused flash self-attention R21. 256 threads = 4 waves = (wr in 0..1 row
// tile of 16) x (wj in 0..1: key-half for QK / dim-half for PV); block owns
// 32 Q-rows; grid 32*NB = 512 blocks -> 2 blocks/CU (barrier drains overlap
// across blocks). Per 32-key tile, ONE barrier (R18's audited scheme):
//   KL[2][c=dim/8][key][8] chunk-major, global_load_lds DMA dbuf. DMA(t+1)
//     issued before QK(t), drained by barrier(t); QK(t+1) reads safe.
//   PL[2][32][40]: P exchange, double-buffered (alternating iters).
//   PV: B-frags straight from global VT[dim][key] (L2-resident, R15-proven
//     addressing) — V never touches LDS. Two 8-frag load/MFMA half-passes
//     bound the register window.
// Deferred normalization via LS. VGPR ~190 < 256 (launch_bounds(256,2));
// LDS 69.3 KB/block -> 138.6 KB per CU at 2 blocks.
__global__ __launch_bounds__(256, 2) void flash_attn(const short* __restrict__ Q,
                                                     const short* __restrict__ Kb,
                                                     const short* __restrict__ VT,
                                                     short* __restrict__ O,
                                                     float scale, int NBm1) {
  __shared__ short KL[2][64 * 256];  // [buf][c][key 0..31][8] = 32 KB each
  __shared__ short PL[2][32 * 40];   // [buf][row 0..31][key 0..31]
  __shared__ float LS[2][32];
  const int lin = blockIdx.x;
  const int b = lin & NBm1;
  const int i0 = (lin >> (31 - __builtin_clz(NBm1 + 1))) * 32;
  const int tid = threadIdx.x;
  const int w = tid >> 6, l = tid & 63, lm = l & 15, quad = l >> 4;
  const int wr = w & 1, wj = w >> 1;

  const short* kbase = Kb + (size_t)b * 524288;
  const short* vbase = VT + (size_t)b * 524288;

  // Q A-frags: rows i0 + wr*16 + lm, all 512 dims (R18-identical).
  bf8 aq[16];
  {
    const short* qb = Q + ((size_t)b * 1024 + i0 + wr * 16 + lm) * 512;
#pragma unroll
    for (int kc = 0; kc < 16; ++kc) aq[kc] = *(const bf8*)&qb[kc * 32 + quad * 8];
  }

  f32x4 oacc[16];
#pragma unroll
  for (int df = 0; df < 16; ++df) oacc[df] = (f32x4){0.f, 0.f, 0.f, 0.f};
  float lsum[4] = {0.f, 0.f, 0.f, 0.f};

  const int kkey = l & 31, kch = l >> 5;  // DMA lane -> (key, chunk-sub)

  // prologue: DMA K tile 0 -> KL[0]; wave w stages chunks w*16 .. w*16+15
  // (8 instrs x 2 chunks each; dest wave-uniform, lane covers (key, sub)).
#pragma unroll
  for (int i = 0; i < 8; ++i) {
    int c0 = w * 16 + i * 2;
    gl_lds16(kbase + (size_t)kkey * 512 + (c0 + kch) * 8, &KL[0][c0 * 256]);
  }
  __syncthreads();  // DMA(0) drained; all waves aligned

  for (int t = 0; t < 32; ++t) {
    const int p = t & 1;
    const int j0 = t * 32;
    if (t < 31) {  // DMA K(t+1) -> KL[p^1]; in flight under QK, drained at barrier
#pragma unroll
      for (int i = 0; i < 8; ++i) {
        int c0 = w * 16 + i * 2;
        gl_lds16(kbase + (size_t)(j0 + 32 + kkey) * 512 + (c0 + kch) * 8,
                 &KL[p ^ 1][c0 * 256]);
      }
    }

    // ---- QK^T: 16 rows (wr) x 16 keys (wj half), K = 512; 2 acc chains ----
    f32x4 s0 = (f32x4){0.f, 0.f, 0.f, 0.f};
    f32x4 s1 = (f32x4){0.f, 0.f, 0.f, 0.f};
    __builtin_amdgcn_s_setprio(1);
#pragma unroll
    for (int kc = 0; kc < 16; kc += 2) {
      bf8 bk0 = *(const bf8*)&KL[p][(kc * 4 + quad) * 256 + (wj * 16 + lm) * 8];
      bf8 bk1 = *(const bf8*)&KL[p][((kc + 1) * 4 + quad) * 256 + (wj * 16 + lm) * 8];
      s0 = __builtin_amdgcn_mfma_f32_16x16x32_bf16(aq[kc], bk0, s0, 0, 0, 0);
      s1 = __builtin_amdgcn_mfma_f32_16x16x32_bf16(aq[kc + 1], bk1, s1, 0, 0, 0);
    }
    __builtin_amdgcn_s_setprio(0);
    f32x4 sacc = s0 + s1;

    // ---- exp + partial row-sum (this wave's 16-key half) + P write ----
#pragma unroll
    for (int r = 0; r < 4; ++r) {
      float e = __expf(sacc[r] * scale);
      float ts = e;
      ts += __shfl_xor(ts, 1);
      ts += __shfl_xor(ts, 2);
      ts += __shfl_xor(ts, 4);
      ts += __shfl_xor(ts, 8);
      lsum[r] += ts;
      PL[p][(wr * 16 + quad * 4 + r) * 40 + wj * 16 + lm] = f2b(e);
    }
    __syncthreads();  // single barrier: PL visible, KL DMA(t+1) drained

    // ---- PV: 16 rows (wr) x 256 dims (wj half), K = 32 keys; V from L2 ----
    bf8 ap = *(const bf8*)&PL[p][(wr * 16 + lm) * 40 + quad * 8];
    const short* vb = vbase + (size_t)(wj * 256 + lm) * 1024 + j0 + quad * 8;
    {
      bf8 bv[8];
#pragma unroll
      for (int df = 0; df < 8; ++df)
        bv[df] = *(const bf8*)&vb[(size_t)(df * 16) * 1024];
      __builtin_amdgcn_s_setprio(1);
#pragma unroll
      for (int df = 0; df < 8; ++df)
        oacc[df] = __builtin_amdgcn_mfma_f32_16x16x32_bf16(ap, bv[df], oacc[df], 0, 0, 0);
      __builtin_amdgcn_s_setprio(0);
    }
    {
      bf8 bv[8];
#pragma unroll
      for (int df = 0; df < 8; ++df)
        bv[df] = *(const bf8*)&vb[(size_t)(128 + df * 16) * 1024];
      __builtin_amdgcn_s_setprio(1);
#pragma unroll
      for (int df = 0; df < 8; ++df)
        oacc[8 + df] = __builtin_amdgcn_mfma_f32_16x16x32_bf16(ap, bv[df], oacc[8 + df], 0, 0, 0);
      __builtin_amdgcn_s_setprio(0);
    }
    // no trailing barrier: next iteration writes the OTHER KL/PL buffers.
  }

  // combine per-key-half row sums, normalize, write out
  if (lm == 0) {
#pragma unroll
    for (int r = 0; r < 4; ++r) LS[wj][wr * 16 + quad * 4 + r] = lsum[r];
  }
  __syncthreads();
  float inv[4];
#pragma unroll
  for (int r = 0; r < 4; ++r) {
    int qr = wr * 16 + quad * 4 + r;
    inv[r] = 1.f / (LS[0][qr] + LS[1][qr]);
  }
  short* ob = O + ((size_t)b * 1024 + i0 + wr * 16 + quad * 4) * 512 + wj * 256;
#pragma unroll
  for (int df = 0; df < 16; ++df)
#pragma unroll
    for (int r = 0; r < 4; ++r)
      ob[(size_t)r * 512 + df * 16 + lm] = f2b(oacc[df][r] * inv[r]);
}

// ---------------------------------------------------------------------------
// Fused cross-attention via MFMA (unchanged).
__global__ __launch_bounds__(256) void cross_attn_mfma(const short* __restrict__ q2,
                                                       const short* __restrict__ k2,
                                                       const short* __restrict__ v2,
                                                       short* __restrict__ o2) {
  __shared__ short Pl[64 * 104];
  __shared__ short VTl[64 * 104];
  const int b = blockIdx.z, h = blockIdx.y, i0 = blockIdx.x * 64;
  const int tid = threadIdx.x;
  const int w = tid >> 6, l = tid & 63, lm = l & 15, quad = l >> 4;

  for (int idx = tid; idx < 64 * 104 / 4; idx += 256)
    *(bf4*)&VTl[idx * 4] = (bf4){0, 0, 0, 0};
  __syncthreads();
  for (int idx = tid; idx < 77 * 64; idx += 256) {
    int j = idx >> 6, d = idx & 63;
    VTl[d * 104 + j] = v2[(size_t)b * 39424 + j * 512 + h * 64 + d];
  }

  const short* qb = q2 + ((size_t)b * 1024 + i0 + w * 16 + lm) * 512 + h * 64;
  bf8 aq0 = *(const bf8*)&qb[quad * 8];
  bf8 aq1 = *(const bf8*)&qb[32 + quad * 8];
  const short* kb = k2 + (size_t)b * 39424 + h * 64;
  f32x4 sacc[5];
#pragma unroll
  for (int jt = 0; jt < 5; ++jt) sacc[jt] = (f32x4){0.f, 0.f, 0.f, 0.f};
#pragma unroll
  for (int jt = 0; jt < 5; ++jt) {
    int j = jt * 16 + lm;
    bf8 b0 = {0, 0, 0, 0, 0, 0, 0, 0}, b1 = {0, 0, 0, 0, 0, 0, 0, 0};
    if (j < 77) {
      b0 = *(const bf8*)&kb[j * 512 + quad * 8];
      b1 = *(const bf8*)&kb[j * 512 + 32 + quad * 8];
    }
    sacc[jt] = __builtin_amdgcn_mfma_f32_16x16x32_bf16(aq0, b0, sacc[jt], 0, 0, 0);
    sacc[jt] = __builtin_amdgcn_mfma_f32_16x16x32_bf16(aq1, b1, sacc[jt], 0, 0, 0);
  }
#pragma unroll
  for (int jt = 0; jt < 5; ++jt) {
    bool valid = (jt * 16 + lm) < 77;
#pragma unroll
    for (int r = 0; r < 4; ++r)
      sacc[jt][r] = valid ? sacc[jt][r] * 0.125f : -1e30f;
  }
#pragma unroll
  for (int r = 0; r < 4; ++r) {
    float mx = sacc[0][r];
#pragma unroll
    for (int jt = 1; jt < 5; ++jt) mx = fmaxf(mx, sacc[jt][r]);
    mx = fmaxf(mx, __shfl_xor(mx, 1));
    mx = fmaxf(mx, __shfl_xor(mx, 2));
    mx = fmaxf(mx, __shfl_xor(mx, 4));
    mx = fmaxf(mx, __shfl_xor(mx, 8));
    float s = 0.f;
    float e[5];
#pragma unroll
    for (int jt = 0; jt < 5; ++jt) { e[jt] = __expf(sacc[jt][r] - mx); s += e[jt]; }
    s += __shfl_xor(s, 1);
    s += __shfl_xor(s, 2);
    s += __shfl_xor(s, 4);
    s += __shfl_xor(s, 8);
    float iv = 1.f / s;
    int row = w * 16 + quad * 4 + r;
#pragma unroll
    for (int jt = 0; jt < 5; ++jt) Pl[row * 104 + jt * 16 + lm] = f2b(e[jt] * iv);
  }
#pragma unroll
  for (int r = 0; r < 4; ++r) Pl[(w * 16 + quad * 4 + r) * 104 + 80 + lm] = 0;
  __syncthreads();

  f32x4 oacc[4];
#pragma unroll
  for (int dt = 0; dt < 4; ++dt) oacc[dt] = (f32x4){0.f, 0.f, 0.f, 0.f};
#pragma unroll
  for (int kc = 0; kc < 3; ++kc) {
    bf8 ap = *(const bf8*)&Pl[(w * 16 + lm) * 104 + kc * 32 + quad * 8];
#pragma unroll
    for (int dt = 0; dt < 4; ++dt) {
      bf8 bv = *(const bf8*)&VTl[(dt * 16 + lm) * 104 + kc * 32 + quad * 8];
      oacc[dt] = __builtin_amdgcn_mfma_f32_16x16x32_bf16(ap, bv, oacc[dt], 0, 0, 0);
    }
  }
  short* ob = o2 + ((size_t)b * 1024 + i0 + w * 16 + quad * 4) * 512 + h * 64;
#pragma unroll
  for (int dt = 0; dt < 4; ++dt)
#pragma unroll
    for (int r = 0; r < 4; ++r)
      ob[(size_t)r * 512 + dt * 16 + lm] = f2b(oacc[dt][r]);
}

// ---------------------------------------------------------------------------
extern "C" void kernel_launch(void* const* d_in, const int* in_sizes, int n_in,
                              void* d_out, int out_size, void* d_ws, size_t ws_size,
                              hipStream_t stream) {
  const void* x       = d_in[0];
  const void* ctx     = d_in[1];
  const void* gn1_g   = d_in[2];
  const void* gn1_b   = d_in[3];
  const void* w_in    = d_in[4];
  const void* b_in    = d_in[5];
  const void* sa_wk   = d_in[6];
  const void* sa_wq   = d_in[7];
  const void* sa_wv   = d_in[8];
  const void* sa_wp   = d_in[9];
  const void* sa_gn_g = d_in[10];
  const void* sa_gn_b = d_in[11];
  const void* ca_wq   = d_in[12];
  const void* ca_wk   = d_in[13];
  const void* ca_wv   = d_in[14];
  const void* ca_wo   = d_in[15];
  const void* ca_bo   = d_in[16];
  const void* w_out   = d_in[17];
  const void* b_out   = d_in[18];

  const int B = 16;
  int NB = 16;
  while (NB > 1 && 131072ull + (size_t)NB * 5767168ull > ws_size) NB >>= 1;

  char* base = reinterpret_cast<char*>(d_ws);
  int* flagp = reinterpret_cast<int*>(base);
  float* smf = reinterpret_cast<float*>(base + 1024);
  float* stats1 = smf;
  float* stats2 = smf + 1024;
  float* s2 = smf + 10240;
  float* t2 = smf + 18432;
  char* big = base + 131072;
  const size_t MB = 1048576;
  short* U0 = (short*)(big + 0 * (size_t)NB * MB);
  short* U1 = (short*)(big + 1 * (size_t)NB * MB);
  short* U2 = (short*)(big + 2 * (size_t)NB * MB);
  short* U3 = (short*)(big + 3 * (size_t)NB * MB);
  short* U4 = (short*)(big + 4 * (size_t)NB * MB);
  char* Sreg = big + 5 * (size_t)NB * MB;
  short* xT = (short*)Sreg;
  short* k2 = (short*)Sreg;
  short* v2 = (short*)(Sreg + (size_t)NB * 78848);

  probe_dtype<<<1, 256, 0, stream>>>((const unsigned short*)x, flagp);

  const float qk_scale = 0.044194173824159216f;
  const int NOSPLIT = 1 << 30;

  for (int b0 = 0; b0 < B; b0 += NB) {
    size_t xoff = (size_t)b0 * 262144;
    size_t coff = (size_t)b0 * 59136;

    gn_stats_ext<<<NB * 32, 256, 0, stream>>>(x, xoff, flagp, stats1, 8, 256, 1024, 32);
    transpose_affine<<<dim3(16, NB), 256, 0, stream>>>(x, xoff, flagp, stats1, gn1_g, gn1_b, xT);
    mm<1, 0, 0, 0, 1, 0><<<dim3(4, 8, NB), 256, 0, stream>>>(
        w_in, 0, 256, 0, xT, 0, 256, 262144, U0, 0, 512, 524288,
        nullptr, 0, 0, 0.f, nullptr, b_in, flagp, 1.f, 1024, 256,
        w_in, U0, NOSPLIT);

    gn_stats2<<<NB * 32, 256, 0, stream>>>(U0, stats2);
    make_affine<<<(NB * 512 + 255) / 256, 256, 0, stream>>>(stats2, sa_gn_g, sa_gn_b, flagp, s2, t2, 512, 16, NB * 512);
    affine_apply<<<NB * 256, 256, 0, stream>>>(U0, s2, t2, U1);

    // q + k merged (independent, share B operand U1): y<8 -> q(U2), y>=8 -> k(U3)
    mm<1, 0, 0, 0, 0, 0><<<dim3(4, 16, NB), 256, 0, stream>>>(
        sa_wq, 0, 512, 0, U1, 0, 512, 524288, U2, 0, 512, 524288,
        nullptr, 0, 0, 0.f, nullptr, nullptr, flagp, 1.f, 1024, 512,
        sa_wk, U3, 8);
    mm<0, 1, 0, 0, 0, 0><<<dim3(8, 4, NB), 256, 0, stream>>>(
        U1, 0, 512, 524288, sa_wv, 0, 512, 0, U4, 0, 1024, 524288,
        nullptr, 0, 0, 0.f, nullptr, nullptr, flagp, 1.f, 512, 512,
        U1, U4, NOSPLIT);

    flash_attn<<<dim3(32 * NB), 256, 0, stream>>>(U2, U3, U4, U1, qk_scale, NB - 1);

    mm<1, 0, 0, 0, 0, 1><<<dim3(4, 8, NB), 256, 0, stream>>>(
        sa_wp, 0, 512, 0, U1, 0, 512, 524288, U3, 0, 512, 524288,
        U0, 0, 524288, 2.f, nullptr, nullptr, flagp, 1.f, 1024, 512,
        sa_wp, U3, NOSPLIT);

    mm<1, 0, 0, 0, 0, 0><<<dim3(4, 8, NB), 256, 0, stream>>>(
        ca_wq, 0, 512, 0, U3, 0, 512, 524288, U2, 0, 512, 524288,
        nullptr, 0, 0, 0.f, nullptr, nullptr, flagp, 1.f, 1024, 512,
        ca_wq, U2, NOSPLIT);
    // ca_wk + ca_wv merged (independent, share B operand ctx): y=0 -> k2, y=1 -> v2
    mm<1, 1, 0, 0, 0, 0><<<dim3(4, 2, NB), 256, 0, stream>>>(
        ca_wk, 0, 768, 0, ctx, coff, 768, 59136, k2, 0, 512, 39424,
        nullptr, 0, 0, 0.f, nullptr, nullptr, flagp, 1.f, 77, 768,
        ca_wv, v2, 1);
    cross_attn_mfma<<<dim3(16, 8, NB), 256, 0, stream>>>(U2, k2, v2, U4);

    mm<1, 0, 0, 0, 1, 1><<<dim3(4, 8, NB), 256, 0, stream>>>(
        ca_wo, 0, 512, 0, U4, 0, 512, 524288, U0, 0, 512, 524288,
        U3, 0, 524288, 1.f, nullptr, ca_bo, flagp, 1.f, 1024, 512,
        ca_wo, U0, NOSPLIT);

    mm<0, 1, 2, 1, 0, 2><<<dim3(8, 2, NB), 256, 0, stream>>>(
        U0, 0, 512, 524288, w_out, 0, 512, 0, d_out, xoff, 1024, 262144,
        x, xoff, 262144, 1.f, b_out, nullptr, flagp, 1.f, 256, 512,
        U0, d_out, NOSPLIT);
  }

  (void)in_sizes; (void)n_in; (void)out_size;
}

// Round 10
// 511.032 us; speedup vs baseline: 1.2500x; 1.1488x over previous
//
#include <hip/hip_runtime.h>
#include <math.h>

#define DEV __device__ __forceinline__

using f32x4 = __attribute__((ext_vector_type(4))) float;
using bf8   = __attribute__((ext_vector_type(8))) short;
using bf4   = __attribute__((ext_vector_type(4))) short;

// B=16, CIN=256, N=1024, INNER=512, CTX_N=77, CTX_D=768, HEADS=8, DH=64.
// Seq-major [n][c] bf16 activations; every GEMM is C=A*B^T with K contiguous.
// Self-attention R22 = R18 exact (measured best: flash 111.6us, total 517.6):
// wr/wj wave split, KL chunk-major DMA dbuf (bank conflicts 33x down),
// VL/PL double-buffered -> ONE barrier per 32-key tile, 2-chain QK.
// Five structural alternatives (R15/R16/R19/R20/R21) all regressed:
// V-from-global exposes L2 latency; >128 VGPR/wave spills; this structure
// is the measured optimum of the family.
// mm: R13's proven version (16x16x32, BK=64, global_load_lds(16B), XOR
// swizzle) + dual-weight merge (independent GEMM pairs in one launch).

DEV short f2b(float x) {
  unsigned u = __builtin_bit_cast(unsigned, x);
  u += 0x7FFFu + ((u >> 16) & 1u);
  return (short)(u >> 16);
}
DEV float b2f(short s) {
  unsigned u = ((unsigned)(unsigned short)s) << 16;
  return __builtin_bit_cast(float, u);
}
DEV float ldin(const void* p, size_t i, int f) {
  return f ? reinterpret_cast<const float*>(p)[i]
           : b2f(reinterpret_cast<const short*>(p)[i]);
}

typedef const __attribute__((address_space(1))) void* gas_t;
typedef __attribute__((address_space(3))) void* las_t;
DEV void gl_lds16(const short* g, short* l) {
  __builtin_amdgcn_global_load_lds((gas_t)g, (las_t)l, 16, 0, 0);
}

DEV float wave_sum(float v) {
#pragma unroll
  for (int off = 32; off > 0; off >>= 1) v += __shfl_xor(v, off);
  return v;
}

// ---------------------------------------------------------------------------
__global__ __launch_bounds__(256) void probe_dtype(const unsigned short* __restrict__ x,
                                                   int* __restrict__ flag) {
  __shared__ int cnt;
  if (threadIdx.x == 0) cnt = 0;
  __syncthreads();
  int c = 0;
  for (int i = threadIdx.x; i < 8192; i += 256) {
    int e = (x[i] >> 7) & 0xFF;
    if (e == 0xFF || e == 0x00) ++c;
  }
  atomicAdd(&cnt, c);
  __syncthreads();
  if (threadIdx.x == 0) flag[0] = (cnt >= 4) ? 1 : 0;
}

// ---------------------------------------------------------------------------
__global__ __launch_bounds__(256) void gn_stats_ext(const void* __restrict__ x, size_t off,
                                                    const int* __restrict__ dflag,
                                                    float* __restrict__ stats,
                                                    int cpg, int C, int N, int G) {
  int f = dflag[0];
  int b = blockIdx.x / G;
  int g = blockIdx.x % G;
  size_t base = off + ((size_t)b * C + (size_t)g * cpg) * N;
  int count = cpg * N;
  float s = 0.f, ss = 0.f;
  if (f) {
    const float* p = (const float*)x + base;
    for (int i = threadIdx.x * 4; i < count; i += 1024) {
      float4 v = *(const float4*)&p[i];
      s += v.x + v.y + v.z + v.w;
      ss += v.x * v.x + v.y * v.y + v.z * v.z + v.w * v.w;
    }
  } else {
    const short* p = (const short*)x + base;
    for (int i = threadIdx.x * 8; i < count; i += 2048) {
      bf8 v = *(const bf8*)&p[i];
#pragma unroll
      for (int j = 0; j < 8; ++j) { float t = b2f(v[j]); s += t; ss += t * t; }
    }
  }
  s = wave_sum(s);
  ss = wave_sum(ss);
  __shared__ float r1[4], r2[4];
  int wid = threadIdx.x >> 6, lane = threadIdx.x & 63;
  if (lane == 0) { r1[wid] = s; r2[wid] = ss; }
  __syncthreads();
  if (threadIdx.x == 0) {
    s = r1[0] + r1[1] + r1[2] + r1[3];
    ss = r2[0] + r2[1] + r2[2] + r2[3];
    float mean = s / (float)count;
    float var = ss / (float)count - mean * mean;
    stats[blockIdx.x * 2 + 0] = mean;
    stats[blockIdx.x * 2 + 1] = rsqrtf(fmaxf(var, 0.f) + 1e-5f);
  }
}

__global__ __launch_bounds__(256) void gn_stats2(const short* __restrict__ h1,
                                                 float* __restrict__ stats) {
  int b = blockIdx.x >> 5, g = blockIdx.x & 31;
  int nr = threadIdx.x >> 1, half = (threadIdx.x & 1) * 8;
  float s = 0.f, ss = 0.f;
  for (int n = nr; n < 1024; n += 128) {
    bf8 v = *(const bf8*)&h1[((size_t)b * 1024 + n) * 512 + g * 16 + half];
#pragma unroll
    for (int j = 0; j < 8; ++j) { float t = b2f(v[j]); s += t; ss += t * t; }
  }
  s = wave_sum(s);
  ss = wave_sum(ss);
  __shared__ float r1[4], r2[4];
  int wid = threadIdx.x >> 6, lane = threadIdx.x & 63;
  if (lane == 0) { r1[wid] = s; r2[wid] = ss; }
  __syncthreads();
  if (threadIdx.x == 0) {
    s = r1[0] + r1[1] + r1[2] + r1[3];
    ss = r2[0] + r2[1] + r2[2] + r2[3];
    float mean = s / 16384.f;
    float var = ss / 16384.f - mean * mean;
    stats[blockIdx.x * 2 + 0] = mean;
    stats[blockIdx.x * 2 + 1] = rsqrtf(fmaxf(var, 0.f) + 1e-5f);
  }
}

__global__ __launch_bounds__(256) void make_affine(const float* __restrict__ stats,
                                                   const void* __restrict__ gamma,
                                                   const void* __restrict__ beta,
                                                   const int* __restrict__ dflag,
                                                   float* __restrict__ sA, float* __restrict__ tA,
                                                   int C, int cpg, int total) {
  int f = dflag[0];
  int i = blockIdx.x * blockDim.x + threadIdx.x;
  if (i >= total) return;
  int b = i / C, c = i % C;
  int G = C / cpg;
  int g = c / cpg;
  float mean = stats[(b * G + g) * 2 + 0];
  float rstd = stats[(b * G + g) * 2 + 1];
  float gm = ldin(gamma, c, f);
  float bt = ldin(beta, c, f);
  sA[i] = rstd * gm;
  tA[i] = bt - mean * rstd * gm;
}

// ---------------------------------------------------------------------------
__global__ __launch_bounds__(256) void transpose_affine(const void* __restrict__ x, size_t xoff,
                                                        const int* __restrict__ dflag,
                                                        const float* __restrict__ stats1,
                                                        const void* __restrict__ gamma,
                                                        const void* __restrict__ beta,
                                                        short* __restrict__ xT) {
  int f = dflag[0];
  __shared__ short xs[64 * 264];
  int b = blockIdx.y, n0 = blockIdx.x * 64;
  int tid = threadIdx.x;
  int cl = tid >> 3;
  int nl8 = (tid & 7) * 8;
#pragma unroll
  for (int p = 0; p < 8; ++p) {
    int c = p * 32 + cl;
    float mean = stats1[(b * 32 + (c >> 3)) * 2 + 0];
    float rstd = stats1[(b * 32 + (c >> 3)) * 2 + 1];
    float gm = ldin(gamma, c, f);
    float bt = ldin(beta, c, f);
    float sA = rstd * gm;
    float tA = bt - mean * sA;
    size_t gidx = xoff + ((size_t)b * 256 + c) * 1024 + n0 + nl8;
    float v[8];
    if (f) {
      const float* px = (const float*)x;
      float4 a = *(const float4*)&px[gidx];
      float4 bb = *(const float4*)&px[gidx + 4];
      v[0] = a.x; v[1] = a.y; v[2] = a.z; v[3] = a.w;
      v[4] = bb.x; v[5] = bb.y; v[6] = bb.z; v[7] = bb.w;
    } else {
      bf8 a = *(const bf8*)&((const short*)x)[gidx];
#pragma unroll
      for (int j = 0; j < 8; ++j) v[j] = b2f(a[j]);
    }
#pragma unroll
    for (int j = 0; j < 8; ++j) xs[(nl8 + j) * 264 + c] = f2b(v[j] * sA + tA);
  }
  __syncthreads();
  int nl = tid >> 2, cch = (tid & 3) * 64;
#pragma unroll
  for (int m = 0; m < 8; ++m)
    *(bf8*)&xT[((size_t)b * 1024 + n0 + nl) * 256 + cch + m * 8] =
        *(const bf8*)&xs[nl * 264 + cch + m * 8];
}

__global__ __launch_bounds__(256) void affine_apply(const short* __restrict__ h1,
                                                    const float* __restrict__ s2,
                                                    const float* __restrict__ t2,
                                                    short* __restrict__ out) {
  size_t gid = (size_t)blockIdx.x * 256 + threadIdx.x;
  size_t base = gid * 8;
  int bl = (int)(base >> 19);
  int c = (int)(base & 511);
  bf8 v = *(const bf8*)&h1[base];
  bf8 o;
#pragma unroll
  for (int j = 0; j < 8; ++j)
    o[j] = f2b(b2f(v[j]) * s2[bl * 512 + c + j] + t2[bl * 512 + c + j]);
  *(bf8*)&out[base] = o;
}

// ---------------------------------------------------------------------------
// Generic MFMA GEMM (R13 version, proven): OUT[z][p][q] = scale *
// sum_k Bm[p][k]*Am[q][k]. BK=64, global_load_lds(16B) staging, 8-chunk XOR
// swizzle, 16x16x32 MFMA. Dual-weight merge: if blockIdx.y >= ysplit, use
// Am2/Out2 with p-tile index (blockIdx.y - ysplit) — merges independent
// GEMM pairs that share the B operand into one launch (kills a stream tail).
template <int A_EXT, int B_EXT, int OUT_T, int BIAS_P_, int BIAS_Q_, int RES_T>
__global__ __launch_bounds__(256) void mm(
    const void* __restrict__ Am, size_t aoff, int lda, size_t zsa,
    const void* __restrict__ Bm, size_t boff, int ldb, size_t zsb,
    void* __restrict__ Out, size_t ooff, int ldc, size_t zsc,
    const void* __restrict__ Res, size_t roff, size_t zsr, float res_scale,
    const void* __restrict__ biasP, const void* __restrict__ biasQ,
    const int* __restrict__ dflag, float scale, int P, int K,
    const void* __restrict__ Am2, void* __restrict__ Out2, int ysplit) {
  const int f = dflag[0];
  __shared__ short lA[128 * 64];
  __shared__ short lB[128 * 64];
  const int tid = threadIdx.x;
  const int z = blockIdx.z;
  int yy = blockIdx.y;
  const void* Ause = Am;
  void* Ouse = Out;
  if (yy >= ysplit) { Ause = Am2; Ouse = Out2; yy -= ysplit; }
  const int q0 = blockIdx.x * 128, p0 = yy * 128;
  const int l = tid & 63;
  const int w = tid >> 6;
  const int wq = (w & 1) * 64, wp = (w >> 1) * 64;
  const int lm = l & 15, quad = l >> 4;
  const int drow = l >> 3;
  const int gchunk = (l & 7) ^ ((l >> 3) & 7);
  const int rx = lm & 7;

  f32x4 acc[4][4];
#pragma unroll
  for (int i = 0; i < 4; ++i)
#pragma unroll
    for (int j = 0; j < 4; ++j) acc[i][j] = (f32x4){0.f, 0.f, 0.f, 0.f};

  for (int kk = 0; kk < K; kk += 64) {
    __syncthreads();
    // ---- stage A tile (rows q0..q0+127, always valid; A = Ause) ----
    if (!(A_EXT && f)) {
      const short* As = (const short*)Ause;
#pragma unroll
      for (int t = 0; t < 4; ++t) {
        int rl = w * 32 + t * 8;
        size_t g = aoff + (size_t)z * zsa + (size_t)(q0 + rl + drow) * lda + kk + gchunk * 8;
        gl_lds16(As + g, &lA[rl * 64]);
      }
    } else {
      const float* p = (const float*)Ause;
      int r = tid >> 1;
      size_t g = aoff + (size_t)z * zsa + (size_t)(q0 + r) * lda + kk;
#pragma unroll
      for (int ci = 0; ci < 4; ++ci) {
        int pc = (tid & 1) * 4 + ci;
        int gc = pc ^ (r & 7);
        short tmp[8];
#pragma unroll
        for (int i2 = 0; i2 < 8; i2 += 4) {
          float4 t4 = *(const float4*)&p[g + gc * 8 + i2];
          tmp[i2] = f2b(t4.x); tmp[i2 + 1] = f2b(t4.y);
          tmp[i2 + 2] = f2b(t4.z); tmp[i2 + 3] = f2b(t4.w);
        }
        *(bf8*)&lA[r * 64 + pc * 8] = *(bf8*)&tmp[0];
      }
    }
    // ---- stage B tile (rows p0..p0+127, guard >= P) ----
    if (!(B_EXT && f)) {
      const short* Bs = (const short*)Bm;
#pragma unroll
      for (int t = 0; t < 4; ++t) {
        int rl = w * 32 + t * 8;
        int r = rl + drow;
        if (p0 + r < P) {
          size_t g = boff + (size_t)z * zsb + (size_t)(p0 + r) * ldb + kk + gchunk * 8;
          gl_lds16(Bs + g, &lB[rl * 64]);
        }
      }
    } else {
      const float* p = (const float*)Bm;
      int r = tid >> 1;
      bool valid = (p0 + r) < P;
      size_t g = boff + (size_t)z * zsb + (size_t)(p0 + r) * ldb + kk;
#pragma unroll
      for (int ci = 0; ci < 4; ++ci) {
        int pc = (tid & 1) * 4 + ci;
        int gc = pc ^ (r & 7);
        short tmp[8] = {0, 0, 0, 0, 0, 0, 0, 0};
        if (valid) {
#pragma unroll
          for (int i2 = 0; i2 < 8; i2 += 4) {
            float4 t4 = *(const float4*)&p[g + gc * 8 + i2];
            tmp[i2] = f2b(t4.x); tmp[i2 + 1] = f2b(t4.y);
            tmp[i2 + 2] = f2b(t4.z); tmp[i2 + 3] = f2b(t4.w);
          }
        }
        *(bf8*)&lB[r * 64 + pc * 8] = *(bf8*)&tmp[0];
      }
    }
    __syncthreads();  // drains vmcnt (DMA) + lgkmcnt before reads

#pragma unroll
    for (int s = 0; s < 2; ++s) {
      bf8 af[4], bfr[4];
#pragma unroll
      for (int i = 0; i < 4; ++i)
        af[i] = *(const bf8*)&lA[(wq + i * 16 + lm) * 64 + (((s * 4 + quad) ^ rx) * 8)];
#pragma unroll
      for (int i = 0; i < 4; ++i)
        bfr[i] = *(const bf8*)&lB[(wp + i * 16 + lm) * 64 + (((s * 4 + quad) ^ rx) * 8)];
#pragma unroll
      for (int qi = 0; qi < 4; ++qi)
#pragma unroll
        for (int pi = 0; pi < 4; ++pi)
          acc[qi][pi] = __builtin_amdgcn_mfma_f32_16x16x32_bf16(af[qi], bfr[pi], acc[qi][pi], 0, 0, 0);
    }
  }

  const size_t obase = ooff + (size_t)z * zsc;
#pragma unroll
  for (int pi = 0; pi < 4; ++pi) {
    int p = p0 + wp + pi * 16 + lm;
    if (p >= P) continue;
    float bp = BIAS_P_ ? ldin(biasP, p, f) : 0.f;
#pragma unroll
    for (int qi = 0; qi < 4; ++qi) {
      int q = q0 + wq + qi * 16 + quad * 4;
      f32x4 d = acc[qi][pi];
      float v[4];
#pragma unroll
      for (int r = 0; r < 4; ++r) {
        v[r] = d[r] * scale + bp;
        if (BIAS_Q_) v[r] += ldin(biasQ, q + r, f);
      }
      if (RES_T == 1) {
        bf4 rv = *(const bf4*)&reinterpret_cast<const short*>(Res)[roff + (size_t)z * zsr + (size_t)p * ldc + q];
#pragma unroll
        for (int r = 0; r < 4; ++r) v[r] += res_scale * b2f(rv[r]);
      } else if (RES_T == 2) {
        size_t ri = roff + (size_t)z * zsr + (size_t)p * ldc + q;
        if (f) {
          float4 rf = *(const float4*)&reinterpret_cast<const float*>(Res)[ri];
          v[0] += res_scale * rf.x; v[1] += res_scale * rf.y;
          v[2] += res_scale * rf.z; v[3] += res_scale * rf.w;
        } else {
          bf4 rv = *(const bf4*)&reinterpret_cast<const short*>(Res)[ri];
#pragma unroll
          for (int r = 0; r < 4; ++r) v[r] += res_scale * b2f(rv[r]);
        }
      }
      size_t idx = obase + (size_t)p * ldc + q;
      if (OUT_T == 0) {
        bf4 o;
#pragma unroll
        for (int r = 0; r < 4; ++r) o[r] = f2b(v[r]);
        *(bf4*)&reinterpret_cast<short*>(Ouse)[idx] = o;
      } else if (OUT_T == 1) {
        f32x4 o = {v[0], v[1], v[2], v[3]};
        *(f32x4*)&reinterpret_cast<float*>(Ouse)[idx] = o;
      } else {
        if (f) {
          f32x4 o = {v[0], v[1], v[2], v[3]};
          *(f32x4*)&reinterpret_cast<float*>(Ouse)[idx] = o;
        } else {
          bf4 o;
#pragma unroll
          for (int r = 0; r < 4; ++r) o[r] = f2b(v[r]);
          *(bf4*)&reinterpret_cast<short*>(Ouse)[idx] = o;
        }
      }
    }
  }
}

// ---------------------------------------------------------------------------
// Fused flash self-attention (R18 exact — measured best 111.6us).
// 512 threads = 8 waves = (wr row-tile x wj key/dim-half). ONE barrier per
// 32-key tile:
//   KL[2]: chunk-major [c][key][8], global_load_lds DMA. DMA(t+1) issued
//     before QK(t); barrier(t)'s vmcnt(0) drains ALL waves' DMA -> QK(t+1)
//     safe. KL[p^1] last read in QK(t-1), complete before barrier(t-1).
//   VL[2]/PL[2]: double-buffered, per-thread-private slots. PV(t) reads
//     buffer p post-barrier(t); writes for t+1 target p^1; a wave can only
//     be one barrier-interval ahead -> 2 buffers suffice (hazards audited).
//   QK accumulator split into 2 chains (s0/s1) — halves the dependent-MFMA
//   latency chain at 2 waves/SIMD.
// LDS 138.5 KB (1 block/CU). Deferred normalization via LS.
__global__ __launch_bounds__(512, 2) void flash_attn(const short* __restrict__ Q,
                                                     const short* __restrict__ Kb,
                                                     const short* __restrict__ VT,
                                                     short* __restrict__ O,
                                                     float scale, int NBm1) {
  __shared__ short KL[2][64 * 256];   // [buf][c][key][8]
  __shared__ short VL[2][4 * 512 * 8];// [buf][kchunk][dim][8]
  __shared__ short PL[2][64 * 40];    // [buf][row][key]
  __shared__ float LS[2][64];
  const int lin = blockIdx.x;
  const int b = lin & NBm1;
  const int i0 = (lin >> (31 - __builtin_clz(NBm1 + 1))) * 64;
  const int tid = threadIdx.x;
  const int w = tid >> 6, l = tid & 63, lm = l & 15, quad = l >> 4;
  const int wr = w & 3, wj = w >> 2;

  const short* kbase = Kb + (size_t)b * 524288;
  const short* vbase = VT + (size_t)b * 524288;

  // Q A-frags: rows i0 + wr*16 + lm, all 512 dims.
  bf8 aq[16];
  {
    const short* qb = Q + ((size_t)b * 1024 + i0 + wr * 16 + lm) * 512;
#pragma unroll
    for (int kc = 0; kc < 16; ++kc) aq[kc] = *(const bf8*)&qb[kc * 32 + quad * 8];
  }

  f32x4 oacc[16];
#pragma unroll
  for (int df = 0; df < 16; ++df) oacc[df] = (f32x4){0.f, 0.f, 0.f, 0.f};
  float lsum[4] = {0.f, 0.f, 0.f, 0.f};

  const int kkey = l & 31, kch = l >> 5;  // DMA lane -> (key, chunk-sub)

  // prologue: V regs for tile 0; DMA K tile 0 -> KL[0] (wave w: c = 8w..8w+7)
  bf8 vreg[4];
  {
    const short* vs = vbase + (size_t)tid * 1024;
#pragma unroll
    for (int i = 0; i < 4; ++i) vreg[i] = *(const bf8*)&vs[i * 8];
#pragma unroll
    for (int i = 0; i < 4; ++i) {
      int c0 = w * 8 + i * 2;
      gl_lds16(kbase + (size_t)kkey * 512 + (c0 + kch) * 8, &KL[0][c0 * 256]);
    }
  }
  __syncthreads();  // DMA(0) drained; all waves aligned

  for (int t = 0; t < 32; ++t) {
    const int p = t & 1;
    const int j0 = t * 32;
    // write V(t) into VL[p]; issue V(t+1) reg loads + K(t+1) DMA -> KL[p^1]
#pragma unroll
    for (int i = 0; i < 4; ++i) *(bf8*)&VL[p][i * 4096 + tid * 8] = vreg[i];
    if (t < 31) {
      const short* vs = vbase + (size_t)tid * 1024 + j0 + 32;
#pragma unroll
      for (int i = 0; i < 4; ++i) vreg[i] = *(const bf8*)&vs[i * 8];
#pragma unroll
      for (int i = 0; i < 4; ++i) {
        int c0 = w * 8 + i * 2;
        gl_lds16(kbase + (size_t)(j0 + 32 + kkey) * 512 + (c0 + kch) * 8,
                 &KL[p ^ 1][c0 * 256]);
      }
    }

    // ---- QK^T: 16 rows (wr) x 16 keys (wj half), K = 512; 2 acc chains ----
    f32x4 s0 = (f32x4){0.f, 0.f, 0.f, 0.f};
    f32x4 s1 = (f32x4){0.f, 0.f, 0.f, 0.f};
    __builtin_amdgcn_s_setprio(1);
#pragma unroll
    for (int kc = 0; kc < 16; kc += 2) {
      bf8 bk0 = *(const bf8*)&KL[p][(kc * 4 + quad) * 256 + (wj * 16 + lm) * 8];
      bf8 bk1 = *(const bf8*)&KL[p][((kc + 1) * 4 + quad) * 256 + (wj * 16 + lm) * 8];
      s0 = __builtin_amdgcn_mfma_f32_16x16x32_bf16(aq[kc], bk0, s0, 0, 0, 0);
      s1 = __builtin_amdgcn_mfma_f32_16x16x32_bf16(aq[kc + 1], bk1, s1, 0, 0, 0);
    }
    __builtin_amdgcn_s_setprio(0);
    f32x4 sacc = s0 + s1;

    // ---- exp + partial row-sum (this wave's 16-key half) + P write ----
#pragma unroll
    for (int r = 0; r < 4; ++r) {
      float e = __expf(sacc[r] * scale);
      float ts = e;
      ts += __shfl_xor(ts, 1);
      ts += __shfl_xor(ts, 2);
      ts += __shfl_xor(ts, 4);
      ts += __shfl_xor(ts, 8);
      lsum[r] += ts;
      PL[p][(wr * 16 + quad * 4 + r) * 40 + wj * 16 + lm] = f2b(e);
    }
    __syncthreads();  // single barrier: P/VL visible, DMA(t+1) drained

    // ---- PV: 16 rows (wr) x 256 dims (wj half), K = 32 keys ----
    bf8 ap = *(const bf8*)&PL[p][(wr * 16 + lm) * 40 + quad * 8];
    __builtin_amdgcn_s_setprio(1);
#pragma unroll
    for (int df = 0; df < 16; ++df) {
      bf8 bv = *(const bf8*)&VL[p][quad * 4096 + (wj * 256 + df * 16 + lm) * 8];
      oacc[df] = __builtin_amdgcn_mfma_f32_16x16x32_bf16(ap, bv, oacc[df], 0, 0, 0);
    }
    __builtin_amdgcn_s_setprio(0);
    // no trailing barrier: next iteration writes target the OTHER buffers.
  }

  // combine per-key-half row sums, normalize, write out
  if (lm == 0) {
#pragma unroll
    for (int r = 0; r < 4; ++r) LS[wj][wr * 16 + quad * 4 + r] = lsum[r];
  }
  __syncthreads();
  float inv[4];
#pragma unroll
  for (int r = 0; r < 4; ++r) {
    int qr = wr * 16 + quad * 4 + r;
    inv[r] = 1.f / (LS[0][qr] + LS[1][qr]);
  }
  short* ob = O + ((size_t)b * 1024 + i0 + wr * 16 + quad * 4) * 512 + wj * 256;
#pragma unroll
  for (int df = 0; df < 16; ++df)
#pragma unroll
    for (int r = 0; r < 4; ++r)
      ob[(size_t)r * 512 + df * 16 + lm] = f2b(oacc[df][r] * inv[r]);
}

// ---------------------------------------------------------------------------
// Fused cross-attention via MFMA (unchanged).
__global__ __launch_bounds__(256) void cross_attn_mfma(const short* __restrict__ q2,
                                                       const short* __restrict__ k2,
                                                       const short* __restrict__ v2,
                                                       short* __restrict__ o2) {
  __shared__ short Pl[64 * 104];
  __shared__ short VTl[64 * 104];
  const int b = blockIdx.z, h = blockIdx.y, i0 = blockIdx.x * 64;
  const int tid = threadIdx.x;
  const int w = tid >> 6, l = tid & 63, lm = l & 15, quad = l >> 4;

  for (int idx = tid; idx < 64 * 104 / 4; idx += 256)
    *(bf4*)&VTl[idx * 4] = (bf4){0, 0, 0, 0};
  __syncthreads();
  for (int idx = tid; idx < 77 * 64; idx += 256) {
    int j = idx >> 6, d = idx & 63;
    VTl[d * 104 + j] = v2[(size_t)b * 39424 + j * 512 + h * 64 + d];
  }

  const short* qb = q2 + ((size_t)b * 1024 + i0 + w * 16 + lm) * 512 + h * 64;
  bf8 aq0 = *(const bf8*)&qb[quad * 8];
  bf8 aq1 = *(const bf8*)&qb[32 + quad * 8];
  const short* kb = k2 + (size_t)b * 39424 + h * 64;
  f32x4 sacc[5];
#pragma unroll
  for (int jt = 0; jt < 5; ++jt) sacc[jt] = (f32x4){0.f, 0.f, 0.f, 0.f};
#pragma unroll
  for (int jt = 0; jt < 5; ++jt) {
    int j = jt * 16 + lm;
    bf8 b0 = {0, 0, 0, 0, 0, 0, 0, 0}, b1 = {0, 0, 0, 0, 0, 0, 0, 0};
    if (j < 77) {
      b0 = *(const bf8*)&kb[j * 512 + quad * 8];
      b1 = *(const bf8*)&kb[j * 512 + 32 + quad * 8];
    }
    sacc[jt] = __builtin_amdgcn_mfma_f32_16x16x32_bf16(aq0, b0, sacc[jt], 0, 0, 0);
    sacc[jt] = __builtin_amdgcn_mfma_f32_16x16x32_bf16(aq1, b1, sacc[jt], 0, 0, 0);
  }
#pragma unroll
  for (int jt = 0; jt < 5; ++jt) {
    bool valid = (jt * 16 + lm) < 77;
#pragma unroll
    for (int r = 0; r < 4; ++r)
      sacc[jt][r] = valid ? sacc[jt][r] * 0.125f : -1e30f;
  }
#pragma unroll
  for (int r = 0; r < 4; ++r) {
    float mx = sacc[0][r];
#pragma unroll
    for (int jt = 1; jt < 5; ++jt) mx = fmaxf(mx, sacc[jt][r]);
    mx = fmaxf(mx, __shfl_xor(mx, 1));
    mx = fmaxf(mx, __shfl_xor(mx, 2));
    mx = fmaxf(mx, __shfl_xor(mx, 4));
    mx = fmaxf(mx, __shfl_xor(mx, 8));
    float s = 0.f;
    float e[5];
#pragma unroll
    for (int jt = 0; jt < 5; ++jt) { e[jt] = __expf(sacc[jt][r] - mx); s += e[jt]; }
    s += __shfl_xor(s, 1);
    s += __shfl_xor(s, 2);
    s += __shfl_xor(s, 4);
    s += __shfl_xor(s, 8);
    float iv = 1.f / s;
    int row = w * 16 + quad * 4 + r;
#pragma unroll
    for (int jt = 0; jt < 5; ++jt) Pl[row * 104 + jt * 16 + lm] = f2b(e[jt] * iv);
  }
#pragma unroll
  for (int r = 0; r < 4; ++r) Pl[(w * 16 + quad * 4 + r) * 104 + 80 + lm] = 0;
  __syncthreads();

  f32x4 oacc[4];
#pragma unroll
  for (int dt = 0; dt < 4; ++dt) oacc[dt] = (f32x4){0.f, 0.f, 0.f, 0.f};
#pragma unroll
  for (int kc = 0; kc < 3; ++kc) {
    bf8 ap = *(const bf8*)&Pl[(w * 16 + lm) * 104 + kc * 32 + quad * 8];
#pragma unroll
    for (int dt = 0; dt < 4; ++dt) {
      bf8 bv = *(const bf8*)&VTl[(dt * 16 + lm) * 104 + kc * 32 + quad * 8];
      oacc[dt] = __builtin_amdgcn_mfma_f32_16x16x32_bf16(ap, bv, oacc[dt], 0, 0, 0);
    }
  }
  short* ob = o2 + ((size_t)b * 1024 + i0 + w * 16 + quad * 4) * 512 + h * 64;
#pragma unroll
  for (int dt = 0; dt < 4; ++dt)
#pragma unroll
    for (int r = 0; r < 4; ++r)
      ob[(size_t)r * 512 + dt * 16 + lm] = f2b(oacc[dt][r]);
}

// ---------------------------------------------------------------------------
extern "C" void kernel_launch(void* const* d_in, const int* in_sizes, int n_in,
                              void* d_out, int out_size, void* d_ws, size_t ws_size,
                              hipStream_t stream) {
  const void* x       = d_in[0];
  const void* ctx     = d_in[1];
  const void* gn1_g   = d_in[2];
  const void* gn1_b   = d_in[3];
  const void* w_in    = d_in[4];
  const void* b_in    = d_in[5];
  const void* sa_wk   = d_in[6];
  const void* sa_wq   = d_in[7];
  const void* sa_wv   = d_in[8];
  const void* sa_wp   = d_in[9];
  const void* sa_gn_g = d_in[10];
  const void* sa_gn_b = d_in[11];
  const void* ca_wq   = d_in[12];
  const void* ca_wk   = d_in[13];
  const void* ca_wv   = d_in[14];
  const void* ca_wo   = d_in[15];
  const void* ca_bo   = d_in[16];
  const void* w_out   = d_in[17];
  const void* b_out   = d_in[18];

  const int B = 16;
  int NB = 16;
  while (NB > 1 && 131072ull + (size_t)NB * 5767168ull > ws_size) NB >>= 1;

  char* base = reinterpret_cast<char*>(d_ws);
  int* flagp = reinterpret_cast<int*>(base);
  float* smf = reinterpret_cast<float*>(base + 1024);
  float* stats1 = smf;
  float* stats2 = smf + 1024;
  float* s2 = smf + 10240;
  float* t2 = smf + 18432;
  char* big = base + 131072;
  const size_t MB = 1048576;
  short* U0 = (short*)(big + 0 * (size_t)NB * MB);
  short* U1 = (short*)(big + 1 * (size_t)NB * MB);
  short* U2 = (short*)(big + 2 * (size_t)NB * MB);
  short* U3 = (short*)(big + 3 * (size_t)NB * MB);
  short* U4 = (short*)(big + 4 * (size_t)NB * MB);
  char* Sreg = big + 5 * (size_t)NB * MB;
  short* xT = (short*)Sreg;
  short* k2 = (short*)Sreg;
  short* v2 = (short*)(Sreg + (size_t)NB * 78848);

  probe_dtype<<<1, 256, 0, stream>>>((const unsigned short*)x, flagp);

  const float qk_scale = 0.044194173824159216f;
  const int NOSPLIT = 1 << 30;

  for (int b0 = 0; b0 < B; b0 += NB) {
    size_t xoff = (size_t)b0 * 262144;
    size_t coff = (size_t)b0 * 59136;

    gn_stats_ext<<<NB * 32, 256, 0, stream>>>(x, xoff, flagp, stats1, 8, 256, 1024, 32);
    transpose_affine<<<dim3(16, NB), 256, 0, stream>>>(x, xoff, flagp, stats1, gn1_g, gn1_b, xT);
    mm<1, 0, 0, 0, 1, 0><<<dim3(4, 8, NB), 256, 0, stream>>>(
        w_in, 0, 256, 0, xT, 0, 256, 262144, U0, 0, 512, 524288,
        nullptr, 0, 0, 0.f, nullptr, b_in, flagp, 1.f, 1024, 256,
        w_in, U0, NOSPLIT);

    gn_stats2<<<NB * 32, 256, 0, stream>>>(U0, stats2);
    make_affine<<<(NB * 512 + 255) / 256, 256, 0, stream>>>(stats2, sa_gn_g, sa_gn_b, flagp, s2, t2, 512, 16, NB * 512);
    affine_apply<<<NB * 256, 256, 0, stream>>>(U0, s2, t2, U1);

    // q + k merged (independent, share B operand U1): y<8 -> q(U2), y>=8 -> k(U3)
    mm<1, 0, 0, 0, 0, 0><<<dim3(4, 16, NB), 256, 0, stream>>>(
        sa_wq, 0, 512, 0, U1, 0, 512, 524288, U2, 0, 512, 524288,
        nullptr, 0, 0, 0.f, nullptr, nullptr, flagp, 1.f, 1024, 512,
        sa_wk, U3, 8);
    mm<0, 1, 0, 0, 0, 0><<<dim3(8, 4, NB), 256, 0, stream>>>(
        U1, 0, 512, 524288, sa_wv, 0, 512, 0, U4, 0, 1024, 524288,
        nullptr, 0, 0, 0.f, nullptr, nullptr, flagp, 1.f, 512, 512,
        U1, U4, NOSPLIT);

    flash_attn<<<dim3(16 * NB), 512, 0, stream>>>(U2, U3, U4, U1, qk_scale, NB - 1);

    mm<1, 0, 0, 0, 0, 1><<<dim3(4, 8, NB), 256, 0, stream>>>(
        sa_wp, 0, 512, 0, U1, 0, 512, 524288, U3, 0, 512, 524288,
        U0, 0, 524288, 2.f, nullptr, nullptr, flagp, 1.f, 1024, 512,
        sa_wp, U3, NOSPLIT);

    mm<1, 0, 0, 0, 0, 0><<<dim3(4, 8, NB), 256, 0, stream>>>(
        ca_wq, 0, 512, 0, U3, 0, 512, 524288, U2, 0, 512, 524288,
        nullptr, 0, 0, 0.f, nullptr, nullptr, flagp, 1.f, 1024, 512,
        ca_wq, U2, NOSPLIT);
    // ca_wk + ca_wv merged (independent, share B operand ctx): y=0 -> k2, y=1 -> v2
    mm<1, 1, 0, 0, 0, 0><<<dim3(4, 2, NB), 256, 0, stream>>>(
        ca_wk, 0, 768, 0, ctx, coff, 768, 59136, k2, 0, 512, 39424,
        nullptr, 0, 0, 0.f, nullptr, nullptr, flagp, 1.f, 77, 768,
        ca_wv, v2, 1);
    cross_attn_mfma<<<dim3(16, 8, NB), 256, 0, stream>>>(U2, k2, v2, U4);

    mm<1, 0, 0, 0, 1, 1><<<dim3(4, 8, NB), 256, 0, stream>>>(
        ca_wo, 0, 512, 0, U4, 0, 512, 524288, U0, 0, 512, 524288,
        U3, 0, 524288, 1.f, nullptr, ca_bo, flagp, 1.f, 1024, 512,
        ca_wo, U0, NOSPLIT);

    mm<0, 1, 2, 1, 0, 2><<<dim3(8, 2, NB), 256, 0, stream>>>(
        U0, 0, 512, 524288, w_out, 0, 512, 0, d_out, xoff, 1024, 262144,
        x, xoff, 262144, 1.f, b_out, nullptr, flagp, 1.f, 256, 512,
        U0, d_out, NOSPLIT);
  }

  (void)in_sizes; (void)n_in; (void)out_size;
}

// Round 11
// 510.265 us; speedup vs baseline: 1.2519x; 1.0015x over previous
//
#include <hip/hip_runtime.h>
#include <math.h>

#define DEV __device__ __forceinline__

using f32x4 = __attribute__((ext_vector_type(4))) float;
using bf8   = __attribute__((ext_vector_type(8))) short;
using bf4   = __attribute__((ext_vector_type(4))) short;

// B=16, CIN=256, N=1024, INNER=512, CTX_N=77, CTX_D=768, HEADS=8, DH=64.
// Seq-major [n][c] bf16 activations; every GEMM is C=A*B^T with K contiguous.
// Self-attention = R18 exact (measured best: flash 110.2us, total 511.0):
// wr/wj wave split, KL chunk-major DMA dbuf, VL/PL dbuf -> ONE barrier per
// 32-key tile, 2-chain QK. Five structural alternatives all regressed.
// R24: gn_stats2 fused into mm(w_in) epilogue (STATS template path) —
// avoids re-reading 32 MB of U0; sums accumulated on the exact stored bf16
// values (b2f(f2b(v))) via wave-reduce + 1 atomicAdd pair per wave per
// channel-group; probe_dtype zeroes the accumulator; make_affine converts
// raw (s,ss) -> (mean, rstd).
// mm: R13's proven version (16x16x32, BK=64, global_load_lds(16B), XOR
// swizzle) + dual-weight merge (independent GEMM pairs in one launch).

DEV short f2b(float x) {
  unsigned u = __builtin_bit_cast(unsigned, x);
  u += 0x7FFFu + ((u >> 16) & 1u);
  return (short)(u >> 16);
}
DEV float b2f(short s) {
  unsigned u = ((unsigned)(unsigned short)s) << 16;
  return __builtin_bit_cast(float, u);
}
DEV float ldin(const void* p, size_t i, int f) {
  return f ? reinterpret_cast<const float*>(p)[i]
           : b2f(reinterpret_cast<const short*>(p)[i]);
}

typedef const __attribute__((address_space(1))) void* gas_t;
typedef __attribute__((address_space(3))) void* las_t;
DEV void gl_lds16(const short* g, short* l) {
  __builtin_amdgcn_global_load_lds((gas_t)g, (las_t)l, 16, 0, 0);
}

DEV float wave_sum(float v) {
#pragma unroll
  for (int off = 32; off > 0; off >>= 1) v += __shfl_xor(v, off);
  return v;
}

// ---------------------------------------------------------------------------
__global__ __launch_bounds__(256) void probe_dtype(const unsigned short* __restrict__ x,
                                                   int* __restrict__ flag,
                                                   float* __restrict__ statsZ) {
  // zero the fused-GN accumulator (raw s/ss sums, 512 groups x 2)
  for (int i = threadIdx.x; i < 1024; i += 256) statsZ[i] = 0.f;
  __shared__ int cnt;
  if (threadIdx.x == 0) cnt = 0;
  __syncthreads();
  int c = 0;
  for (int i = threadIdx.x; i < 8192; i += 256) {
    int e = (x[i] >> 7) & 0xFF;
    if (e == 0xFF || e == 0x00) ++c;
  }
  atomicAdd(&cnt, c);
  __syncthreads();
  if (threadIdx.x == 0) flag[0] = (cnt >= 4) ? 1 : 0;
}

// ---------------------------------------------------------------------------
__global__ __launch_bounds__(256) void gn_stats_ext(const void* __restrict__ x, size_t off,
                                                    const int* __restrict__ dflag,
                                                    float* __restrict__ stats,
                                                    int cpg, int C, int N, int G) {
  int f = dflag[0];
  int b = blockIdx.x / G;
  int g = blockIdx.x % G;
  size_t base = off + ((size_t)b * C + (size_t)g * cpg) * N;
  int count = cpg * N;
  float s = 0.f, ss = 0.f;
  if (f) {
    const float* p = (const float*)x + base;
    for (int i = threadIdx.x * 4; i < count; i += 1024) {
      float4 v = *(const float4*)&p[i];
      s += v.x + v.y + v.z + v.w;
      ss += v.x * v.x + v.y * v.y + v.z * v.z + v.w * v.w;
    }
  } else {
    const short* p = (const short*)x + base;
    for (int i = threadIdx.x * 8; i < count; i += 2048) {
      bf8 v = *(const bf8*)&p[i];
#pragma unroll
      for (int j = 0; j < 8; ++j) { float t = b2f(v[j]); s += t; ss += t * t; }
    }
  }
  s = wave_sum(s);
  ss = wave_sum(ss);
  __shared__ float r1[4], r2[4];
  int wid = threadIdx.x >> 6, lane = threadIdx.x & 63;
  if (lane == 0) { r1[wid] = s; r2[wid] = ss; }
  __syncthreads();
  if (threadIdx.x == 0) {
    s = r1[0] + r1[1] + r1[2] + r1[3];
    ss = r2[0] + r2[1] + r2[2] + r2[3];
    float mean = s / (float)count;
    float var = ss / (float)count - mean * mean;
    stats[blockIdx.x * 2 + 0] = mean;
    stats[blockIdx.x * 2 + 1] = rsqrtf(fmaxf(var, 0.f) + 1e-5f);
  }
}

// make_affine now takes RAW sums (s, ss) accumulated by the mm(w_in)
// epilogue and converts to (mean, rstd) inline. count = cpg * 1024.
__global__ __launch_bounds__(256) void make_affine(const float* __restrict__ stats,
                                                   const void* __restrict__ gamma,
                                                   const void* __restrict__ beta,
                                                   const int* __restrict__ dflag,
                                                   float* __restrict__ sA, float* __restrict__ tA,
                                                   int C, int cpg, int total) {
  int f = dflag[0];
  int i = blockIdx.x * blockDim.x + threadIdx.x;
  if (i >= total) return;
  int b = i / C, c = i % C;
  int G = C / cpg;
  int g = c / cpg;
  float cnt = (float)(cpg * 1024);
  float s = stats[(b * G + g) * 2 + 0];
  float ss = stats[(b * G + g) * 2 + 1];
  float mean = s / cnt;
  float var = ss / cnt - mean * mean;
  float rstd = rsqrtf(fmaxf(var, 0.f) + 1e-5f);
  float gm = ldin(gamma, c, f);
  float bt = ldin(beta, c, f);
  sA[i] = rstd * gm;
  tA[i] = bt - mean * rstd * gm;
}

// ---------------------------------------------------------------------------
__global__ __launch_bounds__(256) void transpose_affine(const void* __restrict__ x, size_t xoff,
                                                        const int* __restrict__ dflag,
                                                        const float* __restrict__ stats1,
                                                        const void* __restrict__ gamma,
                                                        const void* __restrict__ beta,
                                                        short* __restrict__ xT) {
  int f = dflag[0];
  __shared__ short xs[64 * 264];
  int b = blockIdx.y, n0 = blockIdx.x * 64;
  int tid = threadIdx.x;
  int cl = tid >> 3;
  int nl8 = (tid & 7) * 8;
#pragma unroll
  for (int p = 0; p < 8; ++p) {
    int c = p * 32 + cl;
    float mean = stats1[(b * 32 + (c >> 3)) * 2 + 0];
    float rstd = stats1[(b * 32 + (c >> 3)) * 2 + 1];
    float gm = ldin(gamma, c, f);
    float bt = ldin(beta, c, f);
    float sA = rstd * gm;
    float tA = bt - mean * sA;
    size_t gidx = xoff + ((size_t)b * 256 + c) * 1024 + n0 + nl8;
    float v[8];
    if (f) {
      const float* px = (const float*)x;
      float4 a = *(const float4*)&px[gidx];
      float4 bb = *(const float4*)&px[gidx + 4];
      v[0] = a.x; v[1] = a.y; v[2] = a.z; v[3] = a.w;
      v[4] = bb.x; v[5] = bb.y; v[6] = bb.z; v[7] = bb.w;
    } else {
      bf8 a = *(const bf8*)&((const short*)x)[gidx];
#pragma unroll
      for (int j = 0; j < 8; ++j) v[j] = b2f(a[j]);
    }
#pragma unroll
    for (int j = 0; j < 8; ++j) xs[(nl8 + j) * 264 + c] = f2b(v[j] * sA + tA);
  }
  __syncthreads();
  int nl = tid >> 2, cch = (tid & 3) * 64;
#pragma unroll
  for (int m = 0; m < 8; ++m)
    *(bf8*)&xT[((size_t)b * 1024 + n0 + nl) * 256 + cch + m * 8] =
        *(const bf8*)&xs[nl * 264 + cch + m * 8];
}

__global__ __launch_bounds__(256) void affine_apply(const short* __restrict__ h1,
                                                    const float* __restrict__ s2,
                                                    const float* __restrict__ t2,
                                                    short* __restrict__ out) {
  size_t gid = (size_t)blockIdx.x * 256 + threadIdx.x;
  size_t base = gid * 8;
  int bl = (int)(base >> 19);
  int c = (int)(base & 511);
  bf8 v = *(const bf8*)&h1[base];
  bf8 o;
#pragma unroll
  for (int j = 0; j < 8; ++j)
    o[j] = f2b(b2f(v[j]) * s2[bl * 512 + c + j] + t2[bl * 512 + c + j]);
  *(bf8*)&out[base] = o;
}

// ---------------------------------------------------------------------------
// Generic MFMA GEMM (R13 version, proven): OUT[z][p][q] = scale *
// sum_k Bm[p][k]*Am[q][k]. BK=64, global_load_lds(16B) staging, 8-chunk XOR
// swizzle, 16x16x32 MFMA. Dual-weight merge: if blockIdx.y >= ysplit, use
// Am2/Out2 with p-tile index (blockIdx.y - ysplit). STATS=1 (w_in instance):
// epilogue accumulates per-(z, q/16 group) sums of the STORED bf16 values
// into statsAcc (raw s/ss) — replaces the separate gn_stats2 pass.
template <int A_EXT, int B_EXT, int OUT_T, int BIAS_P_, int BIAS_Q_, int RES_T, int STATS>
__global__ __launch_bounds__(256) void mm(
    const void* __restrict__ Am, size_t aoff, int lda, size_t zsa,
    const void* __restrict__ Bm, size_t boff, int ldb, size_t zsb,
    void* __restrict__ Out, size_t ooff, int ldc, size_t zsc,
    const void* __restrict__ Res, size_t roff, size_t zsr, float res_scale,
    const void* __restrict__ biasP, const void* __restrict__ biasQ,
    const int* __restrict__ dflag, float scale, int P, int K,
    const void* __restrict__ Am2, void* __restrict__ Out2, int ysplit,
    float* __restrict__ statsAcc) {
  const int f = dflag[0];
  __shared__ short lA[128 * 64];
  __shared__ short lB[128 * 64];
  const int tid = threadIdx.x;
  const int z = blockIdx.z;
  int yy = blockIdx.y;
  const void* Ause = Am;
  void* Ouse = Out;
  if (yy >= ysplit) { Ause = Am2; Ouse = Out2; yy -= ysplit; }
  const int q0 = blockIdx.x * 128, p0 = yy * 128;
  const int l = tid & 63;
  const int w = tid >> 6;
  const int wq = (w & 1) * 64, wp = (w >> 1) * 64;
  const int lm = l & 15, quad = l >> 4;
  const int drow = l >> 3;
  const int gchunk = (l & 7) ^ ((l >> 3) & 7);
  const int rx = lm & 7;

  f32x4 acc[4][4];
#pragma unroll
  for (int i = 0; i < 4; ++i)
#pragma unroll
    for (int j = 0; j < 4; ++j) acc[i][j] = (f32x4){0.f, 0.f, 0.f, 0.f};

  for (int kk = 0; kk < K; kk += 64) {
    __syncthreads();
    // ---- stage A tile (rows q0..q0+127, always valid; A = Ause) ----
    if (!(A_EXT && f)) {
      const short* As = (const short*)Ause;
#pragma unroll
      for (int t = 0; t < 4; ++t) {
        int rl = w * 32 + t * 8;
        size_t g = aoff + (size_t)z * zsa + (size_t)(q0 + rl + drow) * lda + kk + gchunk * 8;
        gl_lds16(As + g, &lA[rl * 64]);
      }
    } else {
      const float* p = (const float*)Ause;
      int r = tid >> 1;
      size_t g = aoff + (size_t)z * zsa + (size_t)(q0 + r) * lda + kk;
#pragma unroll
      for (int ci = 0; ci < 4; ++ci) {
        int pc = (tid & 1) * 4 + ci;
        int gc = pc ^ (r & 7);
        short tmp[8];
#pragma unroll
        for (int i2 = 0; i2 < 8; i2 += 4) {
          float4 t4 = *(const float4*)&p[g + gc * 8 + i2];
          tmp[i2] = f2b(t4.x); tmp[i2 + 1] = f2b(t4.y);
          tmp[i2 + 2] = f2b(t4.z); tmp[i2 + 3] = f2b(t4.w);
        }
        *(bf8*)&lA[r * 64 + pc * 8] = *(bf8*)&tmp[0];
      }
    }
    // ---- stage B tile (rows p0..p0+127, guard >= P) ----
    if (!(B_EXT && f)) {
      const short* Bs = (const short*)Bm;
#pragma unroll
      for (int t = 0; t < 4; ++t) {
        int rl = w * 32 + t * 8;
        int r = rl + drow;
        if (p0 + r < P) {
          size_t g = boff + (size_t)z * zsb + (size_t)(p0 + r) * ldb + kk + gchunk * 8;
          gl_lds16(Bs + g, &lB[rl * 64]);
        }
      }
    } else {
      const float* p = (const float*)Bm;
      int r = tid >> 1;
      bool valid = (p0 + r) < P;
      size_t g = boff + (size_t)z * zsb + (size_t)(p0 + r) * ldb + kk;
#pragma unroll
      for (int ci = 0; ci < 4; ++ci) {
        int pc = (tid & 1) * 4 + ci;
        int gc = pc ^ (r & 7);
        short tmp[8] = {0, 0, 0, 0, 0, 0, 0, 0};
        if (valid) {
#pragma unroll
          for (int i2 = 0; i2 < 8; i2 += 4) {
            float4 t4 = *(const float4*)&p[g + gc * 8 + i2];
            tmp[i2] = f2b(t4.x); tmp[i2 + 1] = f2b(t4.y);
            tmp[i2 + 2] = f2b(t4.z); tmp[i2 + 3] = f2b(t4.w);
          }
        }
        *(bf8*)&lB[r * 64 + pc * 8] = *(bf8*)&tmp[0];
      }
    }
    __syncthreads();  // drains vmcnt (DMA) + lgkmcnt before reads

#pragma unroll
    for (int s = 0; s < 2; ++s) {
      bf8 af[4], bfr[4];
#pragma unroll
      for (int i = 0; i < 4; ++i)
        af[i] = *(const bf8*)&lA[(wq + i * 16 + lm) * 64 + (((s * 4 + quad) ^ rx) * 8)];
#pragma unroll
      for (int i = 0; i < 4; ++i)
        bfr[i] = *(const bf8*)&lB[(wp + i * 16 + lm) * 64 + (((s * 4 + quad) ^ rx) * 8)];
#pragma unroll
      for (int qi = 0; qi < 4; ++qi)
#pragma unroll
        for (int pi = 0; pi < 4; ++pi)
          acc[qi][pi] = __builtin_amdgcn_mfma_f32_16x16x32_bf16(af[qi], bfr[pi], acc[qi][pi], 0, 0, 0);
    }
  }

  float stS[4] = {0.f, 0.f, 0.f, 0.f};
  float stSS[4] = {0.f, 0.f, 0.f, 0.f};
  const size_t obase = ooff + (size_t)z * zsc;
#pragma unroll
  for (int pi = 0; pi < 4; ++pi) {
    int p = p0 + wp + pi * 16 + lm;
    if (p >= P) continue;
    float bp = BIAS_P_ ? ldin(biasP, p, f) : 0.f;
#pragma unroll
    for (int qi = 0; qi < 4; ++qi) {
      int q = q0 + wq + qi * 16 + quad * 4;
      f32x4 d = acc[qi][pi];
      float v[4];
#pragma unroll
      for (int r = 0; r < 4; ++r) {
        v[r] = d[r] * scale + bp;
        if (BIAS_Q_) v[r] += ldin(biasQ, q + r, f);
      }
      if (RES_T == 1) {
        bf4 rv = *(const bf4*)&reinterpret_cast<const short*>(Res)[roff + (size_t)z * zsr + (size_t)p * ldc + q];
#pragma unroll
        for (int r = 0; r < 4; ++r) v[r] += res_scale * b2f(rv[r]);
      } else if (RES_T == 2) {
        size_t ri = roff + (size_t)z * zsr + (size_t)p * ldc + q;
        if (f) {
          float4 rf = *(const float4*)&reinterpret_cast<const float*>(Res)[ri];
          v[0] += res_scale * rf.x; v[1] += res_scale * rf.y;
          v[2] += res_scale * rf.z; v[3] += res_scale * rf.w;
        } else {
          bf4 rv = *(const bf4*)&reinterpret_cast<const short*>(Res)[ri];
#pragma unroll
          for (int r = 0; r < 4; ++r) v[r] += res_scale * b2f(rv[r]);
        }
      }
      if (STATS) {
#pragma unroll
        for (int r = 0; r < 4; ++r) {
          float rv = b2f(f2b(v[r]));  // exactly the stored bf16 value
          stS[qi] += rv;
          stSS[qi] += rv * rv;
        }
      }
      size_t idx = obase + (size_t)p * ldc + q;
      if (OUT_T == 0) {
        bf4 o;
#pragma unroll
        for (int r = 0; r < 4; ++r) o[r] = f2b(v[r]);
        *(bf4*)&reinterpret_cast<short*>(Ouse)[idx] = o;
      } else if (OUT_T == 1) {
        f32x4 o = {v[0], v[1], v[2], v[3]};
        *(f32x4*)&reinterpret_cast<float*>(Ouse)[idx] = o;
      } else {
        if (f) {
          f32x4 o = {v[0], v[1], v[2], v[3]};
          *(f32x4*)&reinterpret_cast<float*>(Ouse)[idx] = o;
        } else {
          bf4 o;
#pragma unroll
          for (int r = 0; r < 4; ++r) o[r] = f2b(v[r]);
          *(bf4*)&reinterpret_cast<short*>(Ouse)[idx] = o;
        }
      }
    }
  }
  if (STATS) {
    // all 64 lanes of a wave at fixed qi share channel-group g: wave-reduce,
    // one atomic pair per wave per qi (16 adds/counter total across grid).
#pragma unroll
    for (int qi = 0; qi < 4; ++qi) {
      float ws = wave_sum(stS[qi]);
      float wss = wave_sum(stSS[qi]);
      if (l == 0) {
        int g = ((q0 + wq) >> 4) + qi;
        atomicAdd(&statsAcc[((size_t)z * 32 + g) * 2 + 0], ws);
        atomicAdd(&statsAcc[((size_t)z * 32 + g) * 2 + 1], wss);
      }
    }
  }
}

// ---------------------------------------------------------------------------
// Fused flash self-attention (R18 exact — measured best 110.2us).
// 512 threads = 8 waves = (wr row-tile x wj key/dim-half). ONE barrier per
// 32-key tile:
//   KL[2]: chunk-major [c][key][8], global_load_lds DMA. DMA(t+1) issued
//     before QK(t); barrier(t)'s vmcnt(0) drains ALL waves' DMA -> QK(t+1)
//     safe. KL[p^1] last read in QK(t-1), complete before barrier(t-1).
//   VL[2]/PL[2]: double-buffered, per-thread-private slots. PV(t) reads
//     buffer p post-barrier(t); writes for t+1 target p^1; a wave can only
//     be one barrier-interval ahead -> 2 buffers suffice (hazards audited).
//   QK accumulator split into 2 chains (s0/s1).
// LDS 138.5 KB (1 block/CU). Deferred normalization via LS.
__global__ __launch_bounds__(512, 2) void flash_attn(const short* __restrict__ Q,
                                                     const short* __restrict__ Kb,
                                                     const short* __restrict__ VT,
                                                     short* __restrict__ O,
                                                     float scale, int NBm1) {
  __shared__ short KL[2][64 * 256];   // [buf][c][key][8]
  __shared__ short VL[2][4 * 512 * 8];// [buf][kchunk][dim][8]
  __shared__ short PL[2][64 * 40];    // [buf][row][key]
  __shared__ float LS[2][64];
  const int lin = blockIdx.x;
  const int b = lin & NBm1;
  const int i0 = (lin >> (31 - __builtin_clz(NBm1 + 1))) * 64;
  const int tid = threadIdx.x;
  const int w = tid >> 6, l = tid & 63, lm = l & 15, quad = l >> 4;
  const int wr = w & 3, wj = w >> 2;

  const short* kbase = Kb + (size_t)b * 524288;
  const short* vbase = VT + (size_t)b * 524288;

  // Q A-frags: rows i0 + wr*16 + lm, all 512 dims.
  bf8 aq[16];
  {
    const short* qb = Q + ((size_t)b * 1024 + i0 + wr * 16 + lm) * 512;
#pragma unroll
    for (int kc = 0; kc < 16; ++kc) aq[kc] = *(const bf8*)&qb[kc * 32 + quad * 8];
  }

  f32x4 oacc[16];
#pragma unroll
  for (int df = 0; df < 16; ++df) oacc[df] = (f32x4){0.f, 0.f, 0.f, 0.f};
  float lsum[4] = {0.f, 0.f, 0.f, 0.f};

  const int kkey = l & 31, kch = l >> 5;  // DMA lane -> (key, chunk-sub)

  // prologue: V regs for tile 0; DMA K tile 0 -> KL[0] (wave w: c = 8w..8w+7)
  bf8 vreg[4];
  {
    const short* vs = vbase + (size_t)tid * 1024;
#pragma unroll
    for (int i = 0; i < 4; ++i) vreg[i] = *(const bf8*)&vs[i * 8];
#pragma unroll
    for (int i = 0; i < 4; ++i) {
      int c0 = w * 8 + i * 2;
      gl_lds16(kbase + (size_t)kkey * 512 + (c0 + kch) * 8, &KL[0][c0 * 256]);
    }
  }
  __syncthreads();  // DMA(0) drained; all waves aligned

  for (int t = 0; t < 32; ++t) {
    const int p = t & 1;
    const int j0 = t * 32;
    // write V(t) into VL[p]; issue V(t+1) reg loads + K(t+1) DMA -> KL[p^1]
#pragma unroll
    for (int i = 0; i < 4; ++i) *(bf8*)&VL[p][i * 4096 + tid * 8] = vreg[i];
    if (t < 31) {
      const short* vs = vbase + (size_t)tid * 1024 + j0 + 32;
#pragma unroll
      for (int i = 0; i < 4; ++i) vreg[i] = *(const bf8*)&vs[i * 8];
#pragma unroll
      for (int i = 0; i < 4; ++i) {
        int c0 = w * 8 + i * 2;
        gl_lds16(kbase + (size_t)(j0 + 32 + kkey) * 512 + (c0 + kch) * 8,
                 &KL[p ^ 1][c0 * 256]);
      }
    }

    // ---- QK^T: 16 rows (wr) x 16 keys (wj half), K = 512; 2 acc chains ----
    f32x4 s0 = (f32x4){0.f, 0.f, 0.f, 0.f};
    f32x4 s1 = (f32x4){0.f, 0.f, 0.f, 0.f};
    __builtin_amdgcn_s_setprio(1);
#pragma unroll
    for (int kc = 0; kc < 16; kc += 2) {
      bf8 bk0 = *(const bf8*)&KL[p][(kc * 4 + quad) * 256 + (wj * 16 + lm) * 8];
      bf8 bk1 = *(const bf8*)&KL[p][((kc + 1) * 4 + quad) * 256 + (wj * 16 + lm) * 8];
      s0 = __builtin_amdgcn_mfma_f32_16x16x32_bf16(aq[kc], bk0, s0, 0, 0, 0);
      s1 = __builtin_amdgcn_mfma_f32_16x16x32_bf16(aq[kc + 1], bk1, s1, 0, 0, 0);
    }
    __builtin_amdgcn_s_setprio(0);
    f32x4 sacc = s0 + s1;

    // ---- exp + partial row-sum (this wave's 16-key half) + P write ----
#pragma unroll
    for (int r = 0; r < 4; ++r) {
      float e = __expf(sacc[r] * scale);
      float ts = e;
      ts += __shfl_xor(ts, 1);
      ts += __shfl_xor(ts, 2);
      ts += __shfl_xor(ts, 4);
      ts += __shfl_xor(ts, 8);
      lsum[r] += ts;
      PL[p][(wr * 16 + quad * 4 + r) * 40 + wj * 16 + lm] = f2b(e);
    }
    __syncthreads();  // single barrier: P/VL visible, DMA(t+1) drained

    // ---- PV: 16 rows (wr) x 256 dims (wj half), K = 32 keys ----
    bf8 ap = *(const bf8*)&PL[p][(wr * 16 + lm) * 40 + quad * 8];
    __builtin_amdgcn_s_setprio(1);
#pragma unroll
    for (int df = 0; df < 16; ++df) {
      bf8 bv = *(const bf8*)&VL[p][quad * 4096 + (wj * 256 + df * 16 + lm) * 8];
      oacc[df] = __builtin_amdgcn_mfma_f32_16x16x32_bf16(ap, bv, oacc[df], 0, 0, 0);
    }
    __builtin_amdgcn_s_setprio(0);
    // no trailing barrier: next iteration writes target the OTHER buffers.
  }

  // combine per-key-half row sums, normalize, write out
  if (lm == 0) {
#pragma unroll
    for (int r = 0; r < 4; ++r) LS[wj][wr * 16 + quad * 4 + r] = lsum[r];
  }
  __syncthreads();
  float inv[4];
#pragma unroll
  for (int r = 0; r < 4; ++r) {
    int qr = wr * 16 + quad * 4 + r;
    inv[r] = 1.f / (LS[0][qr] + LS[1][qr]);
  }
  short* ob = O + ((size_t)b * 1024 + i0 + wr * 16 + quad * 4) * 512 + wj * 256;
#pragma unroll
  for (int df = 0; df < 16; ++df)
#pragma unroll
    for (int r = 0; r < 4; ++r)
      ob[(size_t)r * 512 + df * 16 + lm] = f2b(oacc[df][r] * inv[r]);
}

// ---------------------------------------------------------------------------
// Fused cross-attention via MFMA (unchanged).
__global__ __launch_bounds__(256) void cross_attn_mfma(const short* __restrict__ q2,
                                                       const short* __restrict__ k2,
                                                       const short* __restrict__ v2,
                                                       short* __restrict__ o2) {
  __shared__ short Pl[64 * 104];
  __shared__ short VTl[64 * 104];
  const int b = blockIdx.z, h = blockIdx.y, i0 = blockIdx.x * 64;
  const int tid = threadIdx.x;
  const int w = tid >> 6, l = tid & 63, lm = l & 15, quad = l >> 4;

  for (int idx = tid; idx < 64 * 104 / 4; idx += 256)
    *(bf4*)&VTl[idx * 4] = (bf4){0, 0, 0, 0};
  __syncthreads();
  for (int idx = tid; idx < 77 * 64; idx += 256) {
    int j = idx >> 6, d = idx & 63;
    VTl[d * 104 + j] = v2[(size_t)b * 39424 + j * 512 + h * 64 + d];
  }

  const short* qb = q2 + ((size_t)b * 1024 + i0 + w * 16 + lm) * 512 + h * 64;
  bf8 aq0 = *(const bf8*)&qb[quad * 8];
  bf8 aq1 = *(const bf8*)&qb[32 + quad * 8];
  const short* kb = k2 + (size_t)b * 39424 + h * 64;
  f32x4 sacc[5];
#pragma unroll
  for (int jt = 0; jt < 5; ++jt) sacc[jt] = (f32x4){0.f, 0.f, 0.f, 0.f};
#pragma unroll
  for (int jt = 0; jt < 5; ++jt) {
    int j = jt * 16 + lm;
    bf8 b0 = {0, 0, 0, 0, 0, 0, 0, 0}, b1 = {0, 0, 0, 0, 0, 0, 0, 0};
    if (j < 77) {
      b0 = *(const bf8*)&kb[j * 512 + quad * 8];
      b1 = *(const bf8*)&kb[j * 512 + 32 + quad * 8];
    }
    sacc[jt] = __builtin_amdgcn_mfma_f32_16x16x32_bf16(aq0, b0, sacc[jt], 0, 0, 0);
    sacc[jt] = __builtin_amdgcn_mfma_f32_16x16x32_bf16(aq1, b1, sacc[jt], 0, 0, 0);
  }
#pragma unroll
  for (int jt = 0; jt < 5; ++jt) {
    bool valid = (jt * 16 + lm) < 77;
#pragma unroll
    for (int r = 0; r < 4; ++r)
      sacc[jt][r] = valid ? sacc[jt][r] * 0.125f : -1e30f;
  }
#pragma unroll
  for (int r = 0; r < 4; ++r) {
    float mx = sacc[0][r];
#pragma unroll
    for (int jt = 1; jt < 5; ++jt) mx = fmaxf(mx, sacc[jt][r]);
    mx = fmaxf(mx, __shfl_xor(mx, 1));
    mx = fmaxf(mx, __shfl_xor(mx, 2));
    mx = fmaxf(mx, __shfl_xor(mx, 4));
    mx = fmaxf(mx, __shfl_xor(mx, 8));
    float s = 0.f;
    float e[5];
#pragma unroll
    for (int jt = 0; jt < 5; ++jt) { e[jt] = __expf(sacc[jt][r] - mx); s += e[jt]; }
    s += __shfl_xor(s, 1);
    s += __shfl_xor(s, 2);
    s += __shfl_xor(s, 4);
    s += __shfl_xor(s, 8);
    float iv = 1.f / s;
    int row = w * 16 + quad * 4 + r;
#pragma unroll
    for (int jt = 0; jt < 5; ++jt) Pl[row * 104 + jt * 16 + lm] = f2b(e[jt] * iv);
  }
#pragma unroll
  for (int r = 0; r < 4; ++r) Pl[(w * 16 + quad * 4 + r) * 104 + 80 + lm] = 0;
  __syncthreads();

  f32x4 oacc[4];
#pragma unroll
  for (int dt = 0; dt < 4; ++dt) oacc[dt] = (f32x4){0.f, 0.f, 0.f, 0.f};
#pragma unroll
  for (int kc = 0; kc < 3; ++kc) {
    bf8 ap = *(const bf8*)&Pl[(w * 16 + lm) * 104 + kc * 32 + quad * 8];
#pragma unroll
    for (int dt = 0; dt < 4; ++dt) {
      bf8 bv = *(const bf8*)&VTl[(dt * 16 + lm) * 104 + kc * 32 + quad * 8];
      oacc[dt] = __builtin_amdgcn_mfma_f32_16x16x32_bf16(ap, bv, oacc[dt], 0, 0, 0);
    }
  }
  short* ob = o2 + ((size_t)b * 1024 + i0 + w * 16 + quad * 4) * 512 + h * 64;
#pragma unroll
  for (int dt = 0; dt < 4; ++dt)
#pragma unroll
    for (int r = 0; r < 4; ++r)
      ob[(size_t)r * 512 + dt * 16 + lm] = f2b(oacc[dt][r]);
}

// ---------------------------------------------------------------------------
extern "C" void kernel_launch(void* const* d_in, const int* in_sizes, int n_in,
                              void* d_out, int out_size, void* d_ws, size_t ws_size,
                              hipStream_t stream) {
  const void* x       = d_in[0];
  const void* ctx     = d_in[1];
  const void* gn1_g   = d_in[2];
  const void* gn1_b   = d_in[3];
  const void* w_in    = d_in[4];
  const void* b_in    = d_in[5];
  const void* sa_wk   = d_in[6];
  const void* sa_wq   = d_in[7];
  const void* sa_wv   = d_in[8];
  const void* sa_wp   = d_in[9];
  const void* sa_gn_g = d_in[10];
  const void* sa_gn_b = d_in[11];
  const void* ca_wq   = d_in[12];
  const void* ca_wk   = d_in[13];
  const void* ca_wv   = d_in[14];
  const void* ca_wo   = d_in[15];
  const void* ca_bo   = d_in[16];
  const void* w_out   = d_in[17];
  const void* b_out   = d_in[18];

  const int B = 16;
  int NB = 16;
  while (NB > 1 && 131072ull + (size_t)NB * 5767168ull > ws_size) NB >>= 1;

  char* base = reinterpret_cast<char*>(d_ws);
  int* flagp = reinterpret_cast<int*>(base);
  float* smf = reinterpret_cast<float*>(base + 1024);
  float* stats1 = smf;
  float* stats2 = smf + 1024;
  float* s2 = smf + 10240;
  float* t2 = smf + 18432;
  char* big = base + 131072;
  const size_t MB = 1048576;
  short* U0 = (short*)(big + 0 * (size_t)NB * MB);
  short* U1 = (short*)(big + 1 * (size_t)NB * MB);
  short* U2 = (short*)(big + 2 * (size_t)NB * MB);
  short* U3 = (short*)(big + 3 * (size_t)NB * MB);
  short* U4 = (short*)(big + 4 * (size_t)NB * MB);
  char* Sreg = big + 5 * (size_t)NB * MB;
  short* xT = (short*)Sreg;
  short* k2 = (short*)Sreg;
  short* v2 = (short*)(Sreg + (size_t)NB * 78848);

  probe_dtype<<<1, 256, 0, stream>>>((const unsigned short*)x, flagp, stats2);

  const float qk_scale = 0.044194173824159216f;
  const int NOSPLIT = 1 << 30;

  for (int b0 = 0; b0 < B; b0 += NB) {
    size_t xoff = (size_t)b0 * 262144;
    size_t coff = (size_t)b0 * 59136;

    gn_stats_ext<<<NB * 32, 256, 0, stream>>>(x, xoff, flagp, stats1, 8, 256, 1024, 32);
    transpose_affine<<<dim3(16, NB), 256, 0, stream>>>(x, xoff, flagp, stats1, gn1_g, gn1_b, xT);
    // w_in GEMM with fused GroupNorm-2 stats accumulation (STATS=1 -> stats2)
    mm<1, 0, 0, 0, 1, 0, 1><<<dim3(4, 8, NB), 256, 0, stream>>>(
        w_in, 0, 256, 0, xT, 0, 256, 262144, U0, 0, 512, 524288,
        nullptr, 0, 0, 0.f, nullptr, b_in, flagp, 1.f, 1024, 256,
        w_in, U0, NOSPLIT, stats2);

    make_affine<<<(NB * 512 + 255) / 256, 256, 0, stream>>>(stats2, sa_gn_g, sa_gn_b, flagp, s2, t2, 512, 16, NB * 512);
    affine_apply<<<NB * 256, 256, 0, stream>>>(U0, s2, t2, U1);

    // q + k merged (independent, share B operand U1): y<8 -> q(U2), y>=8 -> k(U3)
    mm<1, 0, 0, 0, 0, 0, 0><<<dim3(4, 16, NB), 256, 0, stream>>>(
        sa_wq, 0, 512, 0, U1, 0, 512, 524288, U2, 0, 512, 524288,
        nullptr, 0, 0, 0.f, nullptr, nullptr, flagp, 1.f, 1024, 512,
        sa_wk, U3, 8, nullptr);
    mm<0, 1, 0, 0, 0, 0, 0><<<dim3(8, 4, NB), 256, 0, stream>>>(
        U1, 0, 512, 524288, sa_wv, 0, 512, 0, U4, 0, 1024, 524288,
        nullptr, 0, 0, 0.f, nullptr, nullptr, flagp, 1.f, 512, 512,
        U1, U4, NOSPLIT, nullptr);

    flash_attn<<<dim3(16 * NB), 512, 0, stream>>>(U2, U3, U4, U1, qk_scale, NB - 1);

    mm<1, 0, 0, 0, 0, 1, 0><<<dim3(4, 8, NB), 256, 0, stream>>>(
        sa_wp, 0, 512, 0, U1, 0, 512, 524288, U3, 0, 512, 524288,
        U0, 0, 524288, 2.f, nullptr, nullptr, flagp, 1.f, 1024, 512,
        sa_wp, U3, NOSPLIT, nullptr);

    mm<1, 0, 0, 0, 0, 0, 0><<<dim3(4, 8, NB), 256, 0, stream>>>(
        ca_wq, 0, 512, 0, U3, 0, 512, 524288, U2, 0, 512, 524288,
        nullptr, 0, 0, 0.f, nullptr, nullptr, flagp, 1.f, 1024, 512,
        ca_wq, U2, NOSPLIT, nullptr);
    // ca_wk + ca_wv merged (independent, share B operand ctx): y=0 -> k2, y=1 -> v2
    mm<1, 1, 0, 0, 0, 0, 0><<<dim3(4, 2, NB), 256, 0, stream>>>(
        ca_wk, 0, 768, 0, ctx, coff, 768, 59136, k2, 0, 512, 39424,
        nullptr, 0, 0, 0.f, nullptr, nullptr, flagp, 1.f, 77, 768,
        ca_wv, v2, 1, nullptr);
    cross_attn_mfma<<<dim3(16, 8, NB), 256, 0, stream>>>(U2, k2, v2, U4);

    mm<1, 0, 0, 0, 1, 1, 0><<<dim3(4, 8, NB), 256, 0, stream>>>(
        ca_wo, 0, 512, 0, U4, 0, 512, 524288, U0, 0, 512, 524288,
        U3, 0, 524288, 1.f, nullptr, ca_bo, flagp, 1.f, 1024, 512,
        ca_wo, U0, NOSPLIT, nullptr);

    mm<0, 1, 2, 1, 0, 2, 0><<<dim3(8, 2, NB), 256, 0, stream>>>(
        U0, 0, 512, 524288, w_out, 0, 512, 0, d_out, xoff, 1024, 262144,
        x, xoff, 262144, 1.f, b_out, nullptr, flagp, 1.f, 256, 512,
        U0, d_out, NOSPLIT, nullptr);
  }

  (void)in_sizes; (void)n_in; (void)out_size;
}